// Round 12
// baseline (176.397 us; speedup 1.0000x reference)
//
#include <hip/hip_runtime.h>
#include <math.h>

typedef _Float16 f16;
typedef f16 half8 __attribute__((ext_vector_type(8)));
typedef float f32x4 __attribute__((ext_vector_type(4)));

// Problem sizes: B=4, T=2048, G=8, D=128, V=1024
#define BT 8192
#define NG 8
#define ND 128
#define NV 1024
#define MARGIN 0.08f     // 1-term fp16 dist err sigma ~4.5e-3 -> 18 sigma
#define BM 64            // tokens per block
#define BN 32            // codes per tile
#define NT 32            // code tiles

// d_out layout (float32): ids[65536] | quantized_st[8388608] | 3 losses
#define OUT_IDS 0
#define OUT_Q   65536
#define OUT_L   (65536 + 8388608)

// ws float offsets (~1.9 MB)
#define OFF_C2A   0                  // c2 [v*8+g] (recheck)        (8192)
#define OFF_C2B   8192               // c2 [g*NV+v] (gemm)          (8192)
#define OFF_IDS   16384              // ids int                     (65536)
#define OFF_LOSSG 81920              // per-(token,g) loss partial  (65536)
#define OFF_CNT   147456             // flag count                  (8)
#define OFF_FLAGS 147464             // flag list                   (65536)
#define OFF_CBH   213000             // cbh fp16 swizzled stream    (262144 fl)

// ---------------------------------------------------------------------------
// async global->LDS, 16B per lane (linear dest, pre-swizzled source)
// ---------------------------------------------------------------------------
__device__ __forceinline__ void gll16(const f16* g, f16* l) {
    __builtin_amdgcn_global_load_lds(
        (const __attribute__((address_space(1))) unsigned int*)g,
        (__attribute__((address_space(3))) unsigned int*)l, 16, 0, 0);
}

// ---------------------------------------------------------------------------
// prep: c2 (both layouts, R1-exact pairwise-8 order) + fp16(h only) codebook
// written as PRE-SWIZZLED g-blocked 32-row tile chunks:
// stream[(g*32+cn)*4096 + rl*128 + j*8 + e] = fp16(cb[v=cn*32+rl][(j^(rl&7))*8+e])
// float4-vectorized reads; also zeroes the flag counter.
// ---------------------------------------------------------------------------
__global__ __launch_bounds__(256) void prep_kernel(
    const float* __restrict__ cb, f16* __restrict__ cbh,
    float* __restrict__ c2a, float* __restrict__ c2b, int* __restrict__ cnt) {
    int idx = blockIdx.x * 256 + threadIdx.x;   // v*8+g
    if (idx == 0) *cnt = 0;
    int v = idx >> 3, g = idx & 7;
    const float4* row4 = (const float4*)(cb + (size_t)idx * ND);

    float4 v4[32];
#pragma unroll
    for (int i = 0; i < 32; ++i) v4[i] = row4[i];

    // c2: R1 order (d ascending, acc j = d&7, mul+add)
    float r[8];
#pragma unroll
    for (int j = 0; j < 8; ++j) r[j] = 0.0f;
#pragma unroll
    for (int i = 0; i < 32; ++i) {
        int j0 = (i * 4) & 7;
        r[j0 + 0] = __fadd_rn(r[j0 + 0], __fmul_rn(v4[i].x, v4[i].x));
        r[j0 + 1] = __fadd_rn(r[j0 + 1], __fmul_rn(v4[i].y, v4[i].y));
        r[j0 + 2] = __fadd_rn(r[j0 + 2], __fmul_rn(v4[i].z, v4[i].z));
        r[j0 + 3] = __fadd_rn(r[j0 + 3], __fmul_rn(v4[i].w, v4[i].w));
    }
    float s = __fadd_rn(
        __fadd_rn(__fadd_rn(r[0], r[1]), __fadd_rn(r[2], r[3])),
        __fadd_rn(__fadd_rn(r[4], r[5]), __fadd_rn(r[6], r[7])));
    c2a[idx] = s;
    c2b[g * NV + v] = s;

    // h-stream, pre-swizzled
    int cn = v >> 5, rl = v & 31;
    size_t base = ((size_t)(g * 32 + cn)) * 4096 + rl * 128;
#pragma unroll
    for (int j = 0; j < 16; ++j) {
        int js = j ^ (rl & 7);
        float4 a = v4[js * 2], b = v4[js * 2 + 1];
        float vv[8] = {a.x, a.y, a.z, a.w, b.x, b.y, b.z, b.w};
        half8 h;
#pragma unroll
        for (int e = 0; e < 8; ++e) h[e] = (f16)vv[e];
        *(half8*)(cbh + base + j * 8) = h;
    }
}

// ---------------------------------------------------------------------------
// MFMA distance GEMM, pure-fp16 (1 term). Block = 64 tokens x one g; 4 waves
// = 2 token-halves (wr) x 2 code-halves (wc); wave = 32 tokens x 16 codes.
// B: 32 tiles of 32 codes, double-buffered LDS (2x8KB) via global_load_lds
// issued BEFORE compute (R10-proven schedule, 1 barrier/tile). c2 in LDS.
// ~20.7 KB LDS -> 7 blocks/CU.  s = xh*ch; d' = c2 - 2s (x2 cancels in
// argmin). Per-thread running exact top-2; flag iff d2-d1 < MARGIN(=18sigma)
// -> exact recheck: sound. Loss fused: lossg = d1 + x2 (x2 via A-pass +
// butterfly); recheck overwrites flagged entries exactly.
// ---------------------------------------------------------------------------
__global__ __launch_bounds__(256, 4) void mfma_gemm(
    const float* __restrict__ x, const f16* __restrict__ cbh,
    const float* __restrict__ c2b, const int* __restrict__ pad,
    int* __restrict__ ws_ids, float* __restrict__ out_ids,
    float* __restrict__ lossg, int* __restrict__ cnt,
    int* __restrict__ flags) {
    __shared__ __align__(16) f16 Bh[2][BN * ND];   // 2 x 8 KB
    __shared__ __align__(16) float c2s[NV];        // 4 KB
    __shared__ float x2s[BM];                      // 256 B

    const int tid = threadIdx.x;
    const int b = blockIdx.x;
    const int g = b & 7;
    const int tok0 = (b >> 3) * BM;
    const int lane = tid & 63;
    const int w = tid >> 6;
    const int wr = w & 1, wc = w >> 1;
    const int l15 = lane & 15, l4 = lane >> 4;
    const int rw = wc * 16 + l15;            // code row in tile [0,32)

    // prologue: c2 -> LDS, issue tile-0 DMA, then A load/convert under it
    ((float4*)c2s)[tid] = ((const float4*)(c2b + (size_t)g * NV))[tid];
    {
        const f16* sh = cbh + ((size_t)(g * 32 + 0)) * 4096;
        gll16(sh + tid * 8, &Bh[0][tid * 8]);
        gll16(sh + 2048 + tid * 8, &Bh[0][2048 + tid * 8]);
    }

    // A: fp32 read once, fp16 high part only; x2 partial on the side
    half8 ah[4][2];   // [kk][ti]
    float px2[2] = {0.f, 0.f};
#pragma unroll
    for (int kk = 0; kk < 4; ++kk)
#pragma unroll
        for (int ti = 0; ti < 2; ++ti) {
            const float* ap = x + ((size_t)(tok0 + wr * 32 + ti * 16 + l15) * NG + g) * ND
                              + kk * 32 + l4 * 8;
            float4 p0 = *(const float4*)ap, p1 = *(const float4*)(ap + 4);
            float vv[8] = {p0.x, p0.y, p0.z, p0.w, p1.x, p1.y, p1.z, p1.w};
            half8 h;
#pragma unroll
            for (int j = 0; j < 8; ++j) {
                h[j] = (f16)vv[j];
                px2[ti] = fmaf(vv[j], vv[j], px2[ti]);
            }
            ah[kk][ti] = h;
        }
    // butterfly x2 across the 4 l4 groups (lanes xor 16, 32)
#pragma unroll
    for (int ti = 0; ti < 2; ++ti) {
        px2[ti] += __shfl_xor(px2[ti], 16);
        px2[ti] += __shfl_xor(px2[ti], 32);
    }

    float d1s[2][4], d2s[2][4];
    int ids_[2][4];
#pragma unroll
    for (int ti = 0; ti < 2; ++ti)
#pragma unroll
        for (int r = 0; r < 4; ++r) {
            d1s[ti][r] = INFINITY;
            d2s[ti][r] = INFINITY;
            ids_[ti][r] = 0;
        }

    __syncthreads();   // c2 + tile 0 ready

    int buf = 0;
#pragma unroll 1
    for (int t = 0; t < NT; ++t) {
        // issue next tile's DMA (flies under this tile's compute)
        if (t + 1 < NT) {
            const f16* sh = cbh + ((size_t)(g * 32 + t + 1)) * 4096;
            gll16(sh + tid * 8, &Bh[buf ^ 1][tid * 8]);
            gll16(sh + 2048 + tid * 8, &Bh[buf ^ 1][2048 + tid * 8]);
        }

        const int cbase = t * BN + rw;
        f32x4 acc[2];
#pragma unroll
        for (int ti = 0; ti < 2; ++ti) acc[ti] = (f32x4){0.f, 0.f, 0.f, 0.f};

#pragma unroll
        for (int kk = 0; kk < 4; ++kk) {
            int off = rw * 128 + (((kk * 4 + l4) ^ (rw & 7)) << 3);
            half8 bh = *(const half8*)(&Bh[buf][off]);
#pragma unroll
            for (int ti = 0; ti < 2; ++ti)
                acc[ti] = __builtin_amdgcn_mfma_f32_16x16x32_f16(
                    ah[kk][ti], bh, acc[ti], 0, 0, 0);
        }

        float c2v = c2s[cbase];
#pragma unroll
        for (int ti = 0; ti < 2; ++ti)
#pragma unroll
            for (int r = 0; r < 4; ++r) {
                float dv = fmaf(-2.0f, acc[ti][r], c2v);
                if (dv < d1s[ti][r]) {
                    d2s[ti][r] = d1s[ti][r];
                    d1s[ti][r] = dv;
                    ids_[ti][r] = cbase;
                } else {
                    d2s[ti][r] = fminf(d2s[ti][r], dv);
                }
            }

        __syncthreads();   // drains prefetch; all waves done with buf
        buf ^= 1;
    }

    // park x2 per token (wc==0 waves cover all 64 tokens)
    if (wc == 0 && l4 == 0) {
#pragma unroll
        for (int ti = 0; ti < 2; ++ti)
            x2s[wr * 32 + ti * 16 + l15] = px2[ti];
    }

    // merge: 4 xor-shuffle stages over l15 (codes), then across wc via LDS
    float4* red = (float4*)&Bh[0][0];   // overlay, Bh dead
#pragma unroll
    for (int ti = 0; ti < 2; ++ti)
#pragma unroll
        for (int r = 0; r < 4; ++r) {
            float d1 = d1s[ti][r], d2 = d2s[ti][r];
            int id = ids_[ti][r];
#pragma unroll
            for (int m = 1; m < 16; m <<= 1) {
                float od1 = __shfl_xor(d1, m);
                float od2 = __shfl_xor(d2, m);
                int oid = __shfl_xor(id, m);
                if (od1 < d1) { d2 = fminf(d1, od2); d1 = od1; id = oid; }
                else d2 = fminf(d2, fminf(od1, od2));
            }
            if (l15 == 0)
                red[wc * BM + wr * 32 + ti * 16 + l4 * 4 + r] =
                    make_float4(d1, __int_as_float(id), d2, 0.f);
        }
    __syncthreads();

    if (tid < BM) {
        float4 a = red[tid], c = red[BM + tid];
        float d1 = a.x, d2 = a.z;
        int id = __float_as_int(a.y);
        if (c.x < d1) { d2 = fminf(d1, c.z); d1 = c.x; id = __float_as_int(c.y); }
        else d2 = fminf(d2, fminf(c.x, c.z));
        int tok = tok0 + tid;
        int idx = tok * NG + g;
        int p = pad[tok];
        ws_ids[idx] = id;
        out_ids[idx] = p ? -1.0f : (float)id;
        lossg[idx] = p ? 0.0f : (d1 + x2s[tid]);
        if (!p && d2 - d1 < MARGIN) {
            int pos = atomicAdd(cnt, 1);
            flags[pos] = idx;
        }
    }
}

// ---------------------------------------------------------------------------
// exact fp32 recheck, BLOCK per flag: 256 threads, 4 codes/thread (ILP 4),
// x row staged in LDS. R1-identical per-code arithmetic; index tie-break
// == first-occurrence argmin. Also overwrites lossg with the exact value.
// ---------------------------------------------------------------------------
__global__ __launch_bounds__(256) void recheck(
    const float* __restrict__ x, const int* __restrict__ pad,
    const float* __restrict__ cb, const float* __restrict__ c2w,
    const int* __restrict__ cnt, const int* __restrict__ flags,
    int* __restrict__ ws_ids, float* __restrict__ out_ids,
    float* __restrict__ lossg) {
    __shared__ __align__(16) float xs[ND];
    __shared__ float2 redw[4];
    const int tid = threadIdx.x;
    const int lane = tid & 63;
    const int w = tid >> 6;
    const int n_f = cnt[0];

    for (int f = blockIdx.x; f < n_f; f += gridDim.x) {
        int idx = flags[f];
        int g = idx & 7;
        __syncthreads();
        if (tid < 32)
            ((float4*)xs)[tid] = ((const float4*)(x + (size_t)idx * ND))[tid];
        __syncthreads();

        // exact x2 (R1 pairwise-8 order)
        float rr[8];
#pragma unroll
        for (int j = 0; j < 8; ++j) rr[j] = 0.0f;
#pragma unroll
        for (int i = 0; i < 32; ++i) {
            float4 v = ((const float4*)xs)[i];
            int j0 = (i * 4) & 7;
            rr[j0 + 0] = __fadd_rn(rr[j0 + 0], __fmul_rn(v.x, v.x));
            rr[j0 + 1] = __fadd_rn(rr[j0 + 1], __fmul_rn(v.y, v.y));
            rr[j0 + 2] = __fadd_rn(rr[j0 + 2], __fmul_rn(v.z, v.z));
            rr[j0 + 3] = __fadd_rn(rr[j0 + 3], __fmul_rn(v.w, v.w));
        }
        float x2v = __fadd_rn(
            __fadd_rn(__fadd_rn(rr[0], rr[1]), __fadd_rn(rr[2], rr[3])),
            __fadd_rn(__fadd_rn(rr[4], rr[5]), __fadd_rn(rr[6], rr[7])));

        float best = INFINITY;
        int bid = 0x7FFFFFFF;
        float s0 = 0.f, s1 = 0.f, s2 = 0.f, s3 = 0.f;
#pragma unroll
        for (int i = 0; i < 32; ++i) {
            float4 a = ((const float4*)xs)[i];
            float4 q0 = ((const float4*)(cb + ((size_t)(tid) * NG + g) * ND))[i];
            float4 q1 = ((const float4*)(cb + ((size_t)(tid + 256) * NG + g) * ND))[i];
            float4 q2 = ((const float4*)(cb + ((size_t)(tid + 512) * NG + g) * ND))[i];
            float4 q3 = ((const float4*)(cb + ((size_t)(tid + 768) * NG + g) * ND))[i];
            s0 = fmaf(a.x, q0.x, s0); s0 = fmaf(a.y, q0.y, s0);
            s0 = fmaf(a.z, q0.z, s0); s0 = fmaf(a.w, q0.w, s0);
            s1 = fmaf(a.x, q1.x, s1); s1 = fmaf(a.y, q1.y, s1);
            s1 = fmaf(a.z, q1.z, s1); s1 = fmaf(a.w, q1.w, s1);
            s2 = fmaf(a.x, q2.x, s2); s2 = fmaf(a.y, q2.y, s2);
            s2 = fmaf(a.z, q2.z, s2); s2 = fmaf(a.w, q2.w, s2);
            s3 = fmaf(a.x, q3.x, s3); s3 = fmaf(a.y, q3.y, s3);
            s3 = fmaf(a.z, q3.z, s3); s3 = fmaf(a.w, q3.w, s3);
        }
        float dd[4] = {s0, s1, s2, s3};
#pragma unroll
        for (int jj = 0; jj < 4; ++jj) {
            int c = tid + 256 * jj;
            float d = __fadd_rn(__fsub_rn(x2v, __fmul_rn(2.0f, dd[jj])),
                                c2w[(size_t)c * NG + g]);
            if (d < best || (d == best && c < bid)) { best = d; bid = c; }
        }
#pragma unroll
        for (int m = 1; m < 64; m <<= 1) {
            float od = __shfl_xor(best, m);
            int ob = __shfl_xor(bid, m);
            if (od < best || (od == best && ob < bid)) { best = od; bid = ob; }
        }
        if (lane == 0) redw[w] = make_float2(best, __int_as_float(bid));
        __syncthreads();
        if (tid == 0) {
            float b2 = redw[0].x;
            int i2 = __float_as_int(redw[0].y);
#pragma unroll
            for (int ww = 1; ww < 4; ++ww) {
                float ob = redw[ww].x;
                int oi = __float_as_int(redw[ww].y);
                if (ob < b2 || (ob == b2 && oi < i2)) { b2 = ob; i2 = oi; }
            }
            int p = pad[idx >> 3];
            ws_ids[idx] = i2;
            out_ids[idx] = p ? -1.0f : (float)i2;
            lossg[idx] = p ? 0.0f : b2;
        }
    }
}

// ---------------------------------------------------------------------------
// gather: masked write of quantized_st only (loss already fused in gemm).
// ---------------------------------------------------------------------------
__global__ __launch_bounds__(256) void gather_kernel(
    const int* __restrict__ pad, const float* __restrict__ cb,
    const int* __restrict__ ws_ids, float* __restrict__ out_q) {
    const int n = blockIdx.x;
    const int tid = threadIdx.x;
    const int g = tid >> 5;
    const int d4 = tid & 31;

    float4 q = make_float4(0.f, 0.f, 0.f, 0.f);
    if (!pad[n]) {
        int id = ws_ids[n * NG + g];
        q = ((const float4*)(cb + ((size_t)id * NG + g) * ND))[d4];
    }
    ((float4*)(out_q + (size_t)n * (NG * ND)))[tid] = q;
}

// ---------------------------------------------------------------------------
// finalize: deterministic sum of 65536 loss partials + token count
// ---------------------------------------------------------------------------
__global__ __launch_bounds__(256) void final_kernel(
    const int* __restrict__ pad, const float* __restrict__ lossg,
    float* __restrict__ out_l) {
    __shared__ float sr[256];
    __shared__ int mr[256];
    const int tid = threadIdx.x;
    float s = 0.f;
    int m = 0;
    for (int i = tid; i < BT * NG; i += 256) s += lossg[i];
    for (int i = tid; i < BT; i += 256) m += 1 - pad[i];
    sr[tid] = s;
    mr[tid] = m;
    __syncthreads();
    for (int st = 128; st > 0; st >>= 1) {
        if (tid < st) { sr[tid] += sr[tid + st]; mr[tid] += mr[tid + st]; }
        __syncthreads();
    }
    if (tid == 0) {
        float k = sr[0] / (float)mr[0];
        out_l[0] = k;
        out_l[1] = k;
        out_l[2] = k + k;
    }
}

// ---------------------------------------------------------------------------
extern "C" void kernel_launch(void* const* d_in, const int* in_sizes, int n_in,
                              void* d_out, int out_size, void* d_ws, size_t ws_size,
                              hipStream_t stream) {
    const float* x = (const float*)d_in[0];
    const int* pad = (const int*)d_in[1];
    const float* cb = (const float*)d_in[2];
    float* out = (float*)d_out;
    float* ws = (float*)d_ws;

    float* ws_c2a = ws + OFF_C2A;
    float* ws_c2b = ws + OFF_C2B;
    int* ws_ids = (int*)(ws + OFF_IDS);
    float* ws_lossg = ws + OFF_LOSSG;
    int* ws_cnt = (int*)(ws + OFF_CNT);
    int* ws_flags = (int*)(ws + OFF_FLAGS);
    f16* cbh = (f16*)(ws + OFF_CBH);

    prep_kernel<<<NV * NG / 256, 256, 0, stream>>>(cb, cbh, ws_c2a, ws_c2b,
                                                   ws_cnt);
    mfma_gemm<<<(BT / BM) * NG, 256, 0, stream>>>(x, cbh, ws_c2b, pad, ws_ids,
                                                  out + OUT_IDS, ws_lossg,
                                                  ws_cnt, ws_flags);
    recheck<<<2048, 256, 0, stream>>>(x, pad, cb, ws_c2a, ws_cnt, ws_flags,
                                      ws_ids, out + OUT_IDS, ws_lossg);
    gather_kernel<<<BT, 256, 0, stream>>>(pad, cb, ws_ids, out + OUT_Q);
    final_kernel<<<1, 256, 0, stream>>>(pad, ws_lossg, out + OUT_L);
}

// Round 13
// 110.516 us; speedup vs baseline: 1.5961x; 1.5961x over previous
//
#include <hip/hip_runtime.h>
#include <math.h>

typedef _Float16 f16;
typedef f16 half8 __attribute__((ext_vector_type(8)));
typedef float f32x4 __attribute__((ext_vector_type(4)));

// Problem sizes: B=4, T=2048, G=8, D=128, V=1024
#define BT 8192
#define NG 8
#define ND 128
#define NV 1024
#define MARGIN 0.08f     // 1-term fp16 dist err sigma ~4.5e-3 -> 18 sigma
#define BM 64            // tokens per block
#define BN 32            // codes per tile
#define NT 32            // code tiles

// d_out layout (float32): ids[65536] | quantized_st[8388608] | 3 losses
#define OUT_IDS 0
#define OUT_Q   65536
#define OUT_L   (65536 + 8388608)

// ws float offsets (~1.9 MB)
#define OFF_C2A   0                  // c2 [v*8+g] (recheck)        (8192)
#define OFF_C2B   8192               // c2 [g*NV+v] (gemm)          (8192)
#define OFF_IDS   16384              // ids int                     (65536)
#define OFF_LOSSG 81920              // per-(token,g) loss partial  (65536)
#define OFF_CNT   147456             // flag count                  (8)
#define OFF_FLAGS 147464             // flag list                   (65536)
#define OFF_CBH   213000             // cbh fp16 swizzled stream    (262144 fl)
#define OFF_PART  (OFF_CBH + 262144) // loss partials               (64)

// ---------------------------------------------------------------------------
// async global->LDS, 16B per lane (linear dest, pre-swizzled source)
// ---------------------------------------------------------------------------
__device__ __forceinline__ void gll16(const f16* g, f16* l) {
    __builtin_amdgcn_global_load_lds(
        (const __attribute__((address_space(1))) unsigned int*)g,
        (__attribute__((address_space(3))) unsigned int*)l, 16, 0, 0);
}

// ---------------------------------------------------------------------------
// prep: c2 (both layouts, R1-exact pairwise-8 order) + fp16(h only) codebook
// written as PRE-SWIZZLED g-blocked 32-row tile chunks:
// stream[(g*32+cn)*4096 + rl*128 + j*8 + e] = fp16(cb[v=cn*32+rl][(j^(rl&7))*8+e])
// NO register-array row buffer (rule #20: runtime-indexed arrays -> scratch):
// pass 1 streams ascending for c2; pass 2 re-reads from global (L1-hot row).
// ---------------------------------------------------------------------------
__global__ __launch_bounds__(256) void prep_kernel(
    const float* __restrict__ cb, f16* __restrict__ cbh,
    float* __restrict__ c2a, float* __restrict__ c2b, int* __restrict__ cnt) {
    int idx = blockIdx.x * 256 + threadIdx.x;   // v*8+g
    if (idx == 0) *cnt = 0;
    int v = idx >> 3, g = idx & 7;
    const float4* row4 = (const float4*)(cb + (size_t)idx * ND);

    // pass 1: c2, R1 order (d ascending, acc j = d&7, mul+add)
    float r[8];
#pragma unroll
    for (int j = 0; j < 8; ++j) r[j] = 0.0f;
#pragma unroll
    for (int i = 0; i < 32; ++i) {
        float4 vv = row4[i];
        int j0 = (i * 4) & 7;
        r[j0 + 0] = __fadd_rn(r[j0 + 0], __fmul_rn(vv.x, vv.x));
        r[j0 + 1] = __fadd_rn(r[j0 + 1], __fmul_rn(vv.y, vv.y));
        r[j0 + 2] = __fadd_rn(r[j0 + 2], __fmul_rn(vv.z, vv.z));
        r[j0 + 3] = __fadd_rn(r[j0 + 3], __fmul_rn(vv.w, vv.w));
    }
    float s = __fadd_rn(
        __fadd_rn(__fadd_rn(r[0], r[1]), __fadd_rn(r[2], r[3])),
        __fadd_rn(__fadd_rn(r[4], r[5]), __fadd_rn(r[6], r[7])));
    c2a[idx] = s;
    c2b[g * NV + v] = s;

    // pass 2: swizzled fp16 stream; re-read row from global (L1-hot)
    int cn = v >> 5, rl = v & 31;
    size_t base = ((size_t)(g * 32 + cn)) * 4096 + rl * 128;
#pragma unroll
    for (int j = 0; j < 16; ++j) {
        int js = j ^ (rl & 7);
        float4 a = row4[js * 2], b = row4[js * 2 + 1];
        half8 h;
        h[0] = (f16)a.x; h[1] = (f16)a.y; h[2] = (f16)a.z; h[3] = (f16)a.w;
        h[4] = (f16)b.x; h[5] = (f16)b.y; h[6] = (f16)b.z; h[7] = (f16)b.w;
        *(half8*)(cbh + base + j * 8) = h;
    }
}

// ---------------------------------------------------------------------------
// MFMA distance GEMM, pure-fp16 (1 term). Block = 64 tokens x one g; 4 waves
// = 2 token-halves (wr) x 2 code-halves (wc); wave = 32 tokens x 16 codes.
// B: 32 tiles of 32 codes, double-buffered LDS (2x8KB) via global_load_lds
// issued BEFORE compute (R10-proven schedule, 1 barrier/tile). c2 in LDS.
// ~20.7 KB LDS -> 7 blocks/CU.  s = xh*ch; d' = c2 - 2s (x2 cancels in
// argmin). Per-thread running exact top-2; flag iff d2-d1 < MARGIN(=18sigma)
// -> exact recheck: sound. Loss fused: lossg = d1 + x2 (x2 via A-pass +
// butterfly); recheck overwrites flagged entries exactly.
// ---------------------------------------------------------------------------
__global__ __launch_bounds__(256, 4) void mfma_gemm(
    const float* __restrict__ x, const f16* __restrict__ cbh,
    const float* __restrict__ c2b, const int* __restrict__ pad,
    int* __restrict__ ws_ids, float* __restrict__ out_ids,
    float* __restrict__ lossg, int* __restrict__ cnt,
    int* __restrict__ flags) {
    __shared__ __align__(16) f16 Bh[2][BN * ND];   // 2 x 8 KB
    __shared__ __align__(16) float c2s[NV];        // 4 KB
    __shared__ float x2s[BM];                      // 256 B

    const int tid = threadIdx.x;
    const int b = blockIdx.x;
    const int g = b & 7;
    const int tok0 = (b >> 3) * BM;
    const int lane = tid & 63;
    const int w = tid >> 6;
    const int wr = w & 1, wc = w >> 1;
    const int l15 = lane & 15, l4 = lane >> 4;
    const int rw = wc * 16 + l15;            // code row in tile [0,32)

    // prologue: c2 -> LDS, issue tile-0 DMA, then A load/convert under it
    ((float4*)c2s)[tid] = ((const float4*)(c2b + (size_t)g * NV))[tid];
    {
        const f16* sh = cbh + ((size_t)(g * 32 + 0)) * 4096;
        gll16(sh + tid * 8, &Bh[0][tid * 8]);
        gll16(sh + 2048 + tid * 8, &Bh[0][2048 + tid * 8]);
    }

    // A: fp32 read once, fp16 high part only; x2 partial on the side
    half8 ah[4][2];   // [kk][ti]
    float px2[2] = {0.f, 0.f};
#pragma unroll
    for (int kk = 0; kk < 4; ++kk)
#pragma unroll
        for (int ti = 0; ti < 2; ++ti) {
            const float* ap = x + ((size_t)(tok0 + wr * 32 + ti * 16 + l15) * NG + g) * ND
                              + kk * 32 + l4 * 8;
            float4 p0 = *(const float4*)ap, p1 = *(const float4*)(ap + 4);
            float vv[8] = {p0.x, p0.y, p0.z, p0.w, p1.x, p1.y, p1.z, p1.w};
            half8 h;
#pragma unroll
            for (int j = 0; j < 8; ++j) {
                h[j] = (f16)vv[j];
                px2[ti] = fmaf(vv[j], vv[j], px2[ti]);
            }
            ah[kk][ti] = h;
        }
    // butterfly x2 across the 4 l4 groups (lanes xor 16, 32)
#pragma unroll
    for (int ti = 0; ti < 2; ++ti) {
        px2[ti] += __shfl_xor(px2[ti], 16);
        px2[ti] += __shfl_xor(px2[ti], 32);
    }

    float d1s[2][4], d2s[2][4];
    int ids_[2][4];
#pragma unroll
    for (int ti = 0; ti < 2; ++ti)
#pragma unroll
        for (int r = 0; r < 4; ++r) {
            d1s[ti][r] = INFINITY;
            d2s[ti][r] = INFINITY;
            ids_[ti][r] = 0;
        }

    __syncthreads();   // c2 + tile 0 ready

    int buf = 0;
#pragma unroll 1
    for (int t = 0; t < NT; ++t) {
        // issue next tile's DMA (flies under this tile's compute)
        if (t + 1 < NT) {
            const f16* sh = cbh + ((size_t)(g * 32 + t + 1)) * 4096;
            gll16(sh + tid * 8, &Bh[buf ^ 1][tid * 8]);
            gll16(sh + 2048 + tid * 8, &Bh[buf ^ 1][2048 + tid * 8]);
        }

        const int cbase = t * BN + rw;
        f32x4 acc[2];
#pragma unroll
        for (int ti = 0; ti < 2; ++ti) acc[ti] = (f32x4){0.f, 0.f, 0.f, 0.f};

#pragma unroll
        for (int kk = 0; kk < 4; ++kk) {
            int off = rw * 128 + (((kk * 4 + l4) ^ (rw & 7)) << 3);
            half8 bh = *(const half8*)(&Bh[buf][off]);
#pragma unroll
            for (int ti = 0; ti < 2; ++ti)
                acc[ti] = __builtin_amdgcn_mfma_f32_16x16x32_f16(
                    ah[kk][ti], bh, acc[ti], 0, 0, 0);
        }

        float c2v = c2s[cbase];
#pragma unroll
        for (int ti = 0; ti < 2; ++ti)
#pragma unroll
            for (int r = 0; r < 4; ++r) {
                float dv = fmaf(-2.0f, acc[ti][r], c2v);
                if (dv < d1s[ti][r]) {
                    d2s[ti][r] = d1s[ti][r];
                    d1s[ti][r] = dv;
                    ids_[ti][r] = cbase;
                } else {
                    d2s[ti][r] = fminf(d2s[ti][r], dv);
                }
            }

        __syncthreads();   // drains prefetch; all waves done with buf
        buf ^= 1;
    }

    // park x2 per token (wc==0 waves cover all 64 tokens)
    if (wc == 0 && l4 == 0) {
#pragma unroll
        for (int ti = 0; ti < 2; ++ti)
            x2s[wr * 32 + ti * 16 + l15] = px2[ti];
    }

    // merge: 4 xor-shuffle stages over l15 (codes), then across wc via LDS
    float4* red = (float4*)&Bh[0][0];   // overlay, Bh dead
#pragma unroll
    for (int ti = 0; ti < 2; ++ti)
#pragma unroll
        for (int r = 0; r < 4; ++r) {
            float d1 = d1s[ti][r], d2 = d2s[ti][r];
            int id = ids_[ti][r];
#pragma unroll
            for (int m = 1; m < 16; m <<= 1) {
                float od1 = __shfl_xor(d1, m);
                float od2 = __shfl_xor(d2, m);
                int oid = __shfl_xor(id, m);
                if (od1 < d1) { d2 = fminf(d1, od2); d1 = od1; id = oid; }
                else d2 = fminf(d2, fminf(od1, od2));
            }
            if (l15 == 0)
                red[wc * BM + wr * 32 + ti * 16 + l4 * 4 + r] =
                    make_float4(d1, __int_as_float(id), d2, 0.f);
        }
    __syncthreads();

    if (tid < BM) {
        float4 a = red[tid], c = red[BM + tid];
        float d1 = a.x, d2 = a.z;
        int id = __float_as_int(a.y);
        if (c.x < d1) { d2 = fminf(d1, c.z); d1 = c.x; id = __float_as_int(c.y); }
        else d2 = fminf(d2, fminf(c.x, c.z));
        int tok = tok0 + tid;
        int idx = tok * NG + g;
        int p = pad[tok];
        ws_ids[idx] = id;
        out_ids[idx] = p ? -1.0f : (float)id;
        lossg[idx] = p ? 0.0f : (d1 + x2s[tid]);
        if (!p && d2 - d1 < MARGIN) {
            int pos = atomicAdd(cnt, 1);
            flags[pos] = idx;
        }
    }
}

// ---------------------------------------------------------------------------
// exact fp32 recheck, BLOCK per flag: 256 threads, 4 codes/thread (ILP 4),
// x row staged in LDS. R1-identical per-code arithmetic; index tie-break
// == first-occurrence argmin. Also overwrites lossg with the exact value.
// ---------------------------------------------------------------------------
__global__ __launch_bounds__(256) void recheck(
    const float* __restrict__ x, const int* __restrict__ pad,
    const float* __restrict__ cb, const float* __restrict__ c2w,
    const int* __restrict__ cnt, const int* __restrict__ flags,
    int* __restrict__ ws_ids, float* __restrict__ out_ids,
    float* __restrict__ lossg) {
    __shared__ __align__(16) float xs[ND];
    __shared__ float2 redw[4];
    const int tid = threadIdx.x;
    const int lane = tid & 63;
    const int w = tid >> 6;
    const int n_f = cnt[0];

    for (int f = blockIdx.x; f < n_f; f += gridDim.x) {
        int idx = flags[f];
        int g = idx & 7;
        __syncthreads();
        if (tid < 32)
            ((float4*)xs)[tid] = ((const float4*)(x + (size_t)idx * ND))[tid];
        __syncthreads();

        // exact x2 (R1 pairwise-8 order)
        float rr[8];
#pragma unroll
        for (int j = 0; j < 8; ++j) rr[j] = 0.0f;
#pragma unroll
        for (int i = 0; i < 32; ++i) {
            float4 v = ((const float4*)xs)[i];
            int j0 = (i * 4) & 7;
            rr[j0 + 0] = __fadd_rn(rr[j0 + 0], __fmul_rn(v.x, v.x));
            rr[j0 + 1] = __fadd_rn(rr[j0 + 1], __fmul_rn(v.y, v.y));
            rr[j0 + 2] = __fadd_rn(rr[j0 + 2], __fmul_rn(v.z, v.z));
            rr[j0 + 3] = __fadd_rn(rr[j0 + 3], __fmul_rn(v.w, v.w));
        }
        float x2v = __fadd_rn(
            __fadd_rn(__fadd_rn(rr[0], rr[1]), __fadd_rn(rr[2], rr[3])),
            __fadd_rn(__fadd_rn(rr[4], rr[5]), __fadd_rn(rr[6], rr[7])));

        float best = INFINITY;
        int bid = 0x7FFFFFFF;
        float s0 = 0.f, s1 = 0.f, s2 = 0.f, s3 = 0.f;
#pragma unroll
        for (int i = 0; i < 32; ++i) {
            float4 a = ((const float4*)xs)[i];
            float4 q0 = ((const float4*)(cb + ((size_t)(tid) * NG + g) * ND))[i];
            float4 q1 = ((const float4*)(cb + ((size_t)(tid + 256) * NG + g) * ND))[i];
            float4 q2 = ((const float4*)(cb + ((size_t)(tid + 512) * NG + g) * ND))[i];
            float4 q3 = ((const float4*)(cb + ((size_t)(tid + 768) * NG + g) * ND))[i];
            s0 = fmaf(a.x, q0.x, s0); s0 = fmaf(a.y, q0.y, s0);
            s0 = fmaf(a.z, q0.z, s0); s0 = fmaf(a.w, q0.w, s0);
            s1 = fmaf(a.x, q1.x, s1); s1 = fmaf(a.y, q1.y, s1);
            s1 = fmaf(a.z, q1.z, s1); s1 = fmaf(a.w, q1.w, s1);
            s2 = fmaf(a.x, q2.x, s2); s2 = fmaf(a.y, q2.y, s2);
            s2 = fmaf(a.z, q2.z, s2); s2 = fmaf(a.w, q2.w, s2);
            s3 = fmaf(a.x, q3.x, s3); s3 = fmaf(a.y, q3.y, s3);
            s3 = fmaf(a.z, q3.z, s3); s3 = fmaf(a.w, q3.w, s3);
        }
        float dd[4] = {s0, s1, s2, s3};
#pragma unroll
        for (int jj = 0; jj < 4; ++jj) {
            int c = tid + 256 * jj;
            float d = __fadd_rn(__fsub_rn(x2v, __fmul_rn(2.0f, dd[jj])),
                                c2w[(size_t)c * NG + g]);
            if (d < best || (d == best && c < bid)) { best = d; bid = c; }
        }
#pragma unroll
        for (int m = 1; m < 64; m <<= 1) {
            float od = __shfl_xor(best, m);
            int ob = __shfl_xor(bid, m);
            if (od < best || (od == best && ob < bid)) { best = od; bid = ob; }
        }
        if (lane == 0) redw[w] = make_float2(best, __int_as_float(bid));
        __syncthreads();
        if (tid == 0) {
            float b2 = redw[0].x;
            int i2 = __float_as_int(redw[0].y);
#pragma unroll
            for (int ww = 1; ww < 4; ++ww) {
                float ob = redw[ww].x;
                int oi = __float_as_int(redw[ww].y);
                if (ob < b2 || (ob == b2 && oi < i2)) { b2 = ob; i2 = oi; }
            }
            int p = pad[idx >> 3];
            ws_ids[idx] = i2;
            out_ids[idx] = p ? -1.0f : (float)i2;
            lossg[idx] = p ? 0.0f : b2;
        }
    }
}

// ---------------------------------------------------------------------------
// gather: masked write of quantized_st only (loss already fused in gemm).
// ---------------------------------------------------------------------------
__global__ __launch_bounds__(256) void gather_kernel(
    const int* __restrict__ pad, const float* __restrict__ cb,
    const int* __restrict__ ws_ids, float* __restrict__ out_q) {
    const int n = blockIdx.x;
    const int tid = threadIdx.x;
    const int g = tid >> 5;
    const int d4 = tid & 31;

    float4 q = make_float4(0.f, 0.f, 0.f, 0.f);
    if (!pad[n]) {
        int id = ws_ids[n * NG + g];
        q = ((const float4*)(cb + ((size_t)id * NG + g) * ND))[d4];
    }
    ((float4*)(out_q + (size_t)n * (NG * ND)))[tid] = q;
}

// ---------------------------------------------------------------------------
// loss stage 1: 64 blocks x 256 thr, one float4/thread, fixed-order tree
// ---------------------------------------------------------------------------
__global__ __launch_bounds__(256) void loss_part(
    const float* __restrict__ lossg, float* __restrict__ part) {
    __shared__ float sr[256];
    const int tid = threadIdx.x;
    float4 v = ((const float4*)lossg)[blockIdx.x * 256 + tid];
    sr[tid] = ((v.x + v.y) + (v.z + v.w));
    __syncthreads();
    for (int st = 128; st > 0; st >>= 1) {
        if (tid < st) sr[tid] += sr[tid + st];
        __syncthreads();
    }
    if (tid == 0) part[blockIdx.x] = sr[0];
}

// ---------------------------------------------------------------------------
// loss stage 2: deterministic final (64 partials + pad count)
// ---------------------------------------------------------------------------
__global__ __launch_bounds__(256) void final_kernel(
    const int* __restrict__ pad, const float* __restrict__ part,
    float* __restrict__ out_l) {
    __shared__ int mr[256];
    const int tid = threadIdx.x;
    int m = 0;
#pragma unroll
    for (int i = 0; i < 32; ++i) m += 1 - pad[tid * 32 + i];
    mr[tid] = m;
    __syncthreads();
    for (int st = 128; st > 0; st >>= 1) {
        if (tid < st) mr[tid] += mr[tid + st];
        __syncthreads();
    }
    if (tid == 0) {
        float s = 0.f;
#pragma unroll
        for (int i = 0; i < 64; ++i) s += part[i];
        float k = s / (float)mr[0];
        out_l[0] = k;
        out_l[1] = k;
        out_l[2] = k + k;
    }
}

// ---------------------------------------------------------------------------
extern "C" void kernel_launch(void* const* d_in, const int* in_sizes, int n_in,
                              void* d_out, int out_size, void* d_ws, size_t ws_size,
                              hipStream_t stream) {
    const float* x = (const float*)d_in[0];
    const int* pad = (const int*)d_in[1];
    const float* cb = (const float*)d_in[2];
    float* out = (float*)d_out;
    float* ws = (float*)d_ws;

    float* ws_c2a = ws + OFF_C2A;
    float* ws_c2b = ws + OFF_C2B;
    int* ws_ids = (int*)(ws + OFF_IDS);
    float* ws_lossg = ws + OFF_LOSSG;
    int* ws_cnt = (int*)(ws + OFF_CNT);
    int* ws_flags = (int*)(ws + OFF_FLAGS);
    f16* cbh = (f16*)(ws + OFF_CBH);
    float* ws_part = ws + OFF_PART;

    prep_kernel<<<NV * NG / 256, 256, 0, stream>>>(cb, cbh, ws_c2a, ws_c2b,
                                                   ws_cnt);
    mfma_gemm<<<(BT / BM) * NG, 256, 0, stream>>>(x, cbh, ws_c2b, pad, ws_ids,
                                                  out + OUT_IDS, ws_lossg,
                                                  ws_cnt, ws_flags);
    recheck<<<2048, 256, 0, stream>>>(x, pad, cb, ws_c2a, ws_cnt, ws_flags,
                                      ws_ids, out + OUT_IDS, ws_lossg);
    gather_kernel<<<BT, 256, 0, stream>>>(pad, cb, ws_ids, out + OUT_Q);
    loss_part<<<64, 256, 0, stream>>>(ws_lossg, ws_part);
    final_kernel<<<1, 256, 0, stream>>>(pad, ws_part, out + OUT_L);
}

// Round 14
// 105.342 us; speedup vs baseline: 1.6745x; 1.0491x over previous
//
#include <hip/hip_runtime.h>
#include <math.h>

typedef _Float16 f16;
typedef f16 half8 __attribute__((ext_vector_type(8)));
typedef float f32x4 __attribute__((ext_vector_type(4)));

// Problem sizes: B=4, T=2048, G=8, D=128, V=1024
#define BT 8192
#define NG 8
#define ND 128
#define NV 1024
#define MARGIN 0.08f     // 1-term fp16 dist err sigma ~4.5e-3 -> 18 sigma
#define BM 64            // tokens per block
#define BN 32            // codes per tile
#define NT 32            // code tiles

// d_out layout (float32): ids[65536] | quantized_st[8388608] | 3 losses
#define OUT_IDS 0
#define OUT_Q   65536
#define OUT_L   (65536 + 8388608)

// ws float offsets (~1.9 MB)
#define OFF_C2A   0                  // c2 [v*8+g] (recheck)        (8192)
#define OFF_C2B   8192               // c2 [g*NV+v] (gemm)          (8192)
#define OFF_IDS   16384              // ids int                     (65536)
#define OFF_LOSSG 81920              // per-(token,g) loss partial  (65536)
#define OFF_CNT   147456             // flag count                  (8)
#define OFF_FLAGS 147464             // flag list                   (65536)
#define OFF_CBH   213000             // cbh fp16 swizzled stream    (262144 fl)
#define OFF_PART  (OFF_CBH + 262144) // loss partials               (64)

// ---------------------------------------------------------------------------
// async global->LDS, 16B per lane (linear dest, pre-swizzled source)
// ---------------------------------------------------------------------------
__device__ __forceinline__ void gll16(const f16* g, f16* l) {
    __builtin_amdgcn_global_load_lds(
        (const __attribute__((address_space(1))) unsigned int*)g,
        (__attribute__((address_space(3))) unsigned int*)l, 16, 0, 0);
}

// ---------------------------------------------------------------------------
// prep: c2 (both layouts, R1-exact pairwise-8 order) + fp16(h only) codebook
// as PRE-SWIZZLED g-blocked 32-row tile chunks. No runtime-indexed register
// arrays (rule #20): pass 2 re-reads the row from global (L1-hot).
// ---------------------------------------------------------------------------
__global__ __launch_bounds__(256) void prep_kernel(
    const float* __restrict__ cb, f16* __restrict__ cbh,
    float* __restrict__ c2a, float* __restrict__ c2b, int* __restrict__ cnt) {
    int idx = blockIdx.x * 256 + threadIdx.x;   // v*8+g
    if (idx == 0) *cnt = 0;
    int v = idx >> 3, g = idx & 7;
    const float4* row4 = (const float4*)(cb + (size_t)idx * ND);

    float r[8];
#pragma unroll
    for (int j = 0; j < 8; ++j) r[j] = 0.0f;
#pragma unroll
    for (int i = 0; i < 32; ++i) {
        float4 vv = row4[i];
        int j0 = (i * 4) & 7;
        r[j0 + 0] = __fadd_rn(r[j0 + 0], __fmul_rn(vv.x, vv.x));
        r[j0 + 1] = __fadd_rn(r[j0 + 1], __fmul_rn(vv.y, vv.y));
        r[j0 + 2] = __fadd_rn(r[j0 + 2], __fmul_rn(vv.z, vv.z));
        r[j0 + 3] = __fadd_rn(r[j0 + 3], __fmul_rn(vv.w, vv.w));
    }
    float s = __fadd_rn(
        __fadd_rn(__fadd_rn(r[0], r[1]), __fadd_rn(r[2], r[3])),
        __fadd_rn(__fadd_rn(r[4], r[5]), __fadd_rn(r[6], r[7])));
    c2a[idx] = s;
    c2b[g * NV + v] = s;

    int cn = v >> 5, rl = v & 31;
    size_t base = ((size_t)(g * 32 + cn)) * 4096 + rl * 128;
#pragma unroll
    for (int j = 0; j < 16; ++j) {
        int js = j ^ (rl & 7);
        float4 a = row4[js * 2], b = row4[js * 2 + 1];
        half8 h;
        h[0] = (f16)a.x; h[1] = (f16)a.y; h[2] = (f16)a.z; h[3] = (f16)a.w;
        h[4] = (f16)b.x; h[5] = (f16)b.y; h[6] = (f16)b.z; h[7] = (f16)b.w;
        *(half8*)(cbh + base + j * 8) = h;
    }
}

// ---------------------------------------------------------------------------
// MFMA distance GEMM, pure-fp16, R11-sync + R13-occupancy + fused gather.
// Block = 64 tokens x one g; 4 waves = 2 token-halves x 2 code-halves.
// Per-tile schedule (counted-wait, no prefetch drain):
//   s_waitcnt vmcnt(0) lgkmcnt(0)  [tile t's loads: had ALL of tile t-1 to fly]
//   raw s_barrier + sched_barrier(0)
//   issue tile t+1 DMA  [crosses the next barrier un-drained]
//   compute tile t
// d' = c2 - 2*(xh.ch); exact per-thread running top-2; flag iff
// d2-d1 < MARGIN (18 sigma) -> exact recheck (sound). lossg = d1 + x2 fused.
// Tail: quantized_st rows written here (gather kernel deleted); ids via LDS.
// ---------------------------------------------------------------------------
__global__ __launch_bounds__(256, 4) void mfma_gemm(
    const float* __restrict__ x, const f16* __restrict__ cbh,
    const float* __restrict__ cb, const float* __restrict__ c2b,
    const int* __restrict__ pad, int* __restrict__ ws_ids,
    float* __restrict__ out_ids, float* __restrict__ out_q,
    float* __restrict__ lossg, int* __restrict__ cnt,
    int* __restrict__ flags) {
    __shared__ __align__(16) f16 Bh[2][BN * ND];   // 2 x 8 KB
    __shared__ __align__(16) float c2s[NV];        // 4 KB
    __shared__ float x2s[BM];                      // 256 B
    __shared__ int idsL[BM];                       // 256 B

    const int tid = threadIdx.x;
    const int b = blockIdx.x;
    const int g = b & 7;
    const int tok0 = (b >> 3) * BM;
    const int lane = tid & 63;
    const int w = tid >> 6;
    const int wr = w & 1, wc = w >> 1;
    const int l15 = lane & 15, l4 = lane >> 4;
    const int rw = wc * 16 + l15;            // code row in tile [0,32)

    // prologue: c2 -> LDS, issue tile-0 DMA, A load/convert under it
    ((float4*)c2s)[tid] = ((const float4*)(c2b + (size_t)g * NV))[tid];
    {
        const f16* sh = cbh + ((size_t)(g * 32 + 0)) * 4096;
        gll16(sh + tid * 8, &Bh[0][tid * 8]);
        gll16(sh + 2048 + tid * 8, &Bh[0][2048 + tid * 8]);
    }

    half8 ah[4][2];   // [kk][ti]
    float px2[2] = {0.f, 0.f};
#pragma unroll
    for (int kk = 0; kk < 4; ++kk)
#pragma unroll
        for (int ti = 0; ti < 2; ++ti) {
            const float* ap = x + ((size_t)(tok0 + wr * 32 + ti * 16 + l15) * NG + g) * ND
                              + kk * 32 + l4 * 8;
            float4 p0 = *(const float4*)ap, p1 = *(const float4*)(ap + 4);
            float vv[8] = {p0.x, p0.y, p0.z, p0.w, p1.x, p1.y, p1.z, p1.w};
            half8 h;
#pragma unroll
            for (int j = 0; j < 8; ++j) {
                h[j] = (f16)vv[j];
                px2[ti] = fmaf(vv[j], vv[j], px2[ti]);
            }
            ah[kk][ti] = h;
        }
#pragma unroll
    for (int ti = 0; ti < 2; ++ti) {
        px2[ti] += __shfl_xor(px2[ti], 16);
        px2[ti] += __shfl_xor(px2[ti], 32);
    }

    float d1s[2][4], d2s[2][4];
    int ids_[2][4];
#pragma unroll
    for (int ti = 0; ti < 2; ++ti)
#pragma unroll
        for (int r = 0; r < 4; ++r) {
            d1s[ti][r] = INFINITY;
            d2s[ti][r] = INFINITY;
            ids_[ti][r] = 0;
        }

    int buf = 0;
#pragma unroll 1
    for (int t = 0; t < NT; ++t) {
        // wait ONLY tile t's loads (they had all of tile t-1 to fly)
        asm volatile("s_waitcnt vmcnt(0) lgkmcnt(0)" ::: "memory");
        __builtin_amdgcn_s_barrier();
        __builtin_amdgcn_sched_barrier(0);

        // issue tile t+1 (crosses the next barrier un-drained)
        if (t + 1 < NT) {
            const f16* sh = cbh + ((size_t)(g * 32 + t + 1)) * 4096;
            gll16(sh + tid * 8, &Bh[buf ^ 1][tid * 8]);
            gll16(sh + 2048 + tid * 8, &Bh[buf ^ 1][2048 + tid * 8]);
        }

        const int cbase = t * BN + rw;
        f32x4 acc[2];
#pragma unroll
        for (int ti = 0; ti < 2; ++ti) acc[ti] = (f32x4){0.f, 0.f, 0.f, 0.f};

#pragma unroll
        for (int kk = 0; kk < 4; ++kk) {
            int off = rw * 128 + (((kk * 4 + l4) ^ (rw & 7)) << 3);
            half8 bh = *(const half8*)(&Bh[buf][off]);
#pragma unroll
            for (int ti = 0; ti < 2; ++ti)
                acc[ti] = __builtin_amdgcn_mfma_f32_16x16x32_f16(
                    ah[kk][ti], bh, acc[ti], 0, 0, 0);
        }

        float c2v = c2s[cbase];
#pragma unroll
        for (int ti = 0; ti < 2; ++ti)
#pragma unroll
            for (int r = 0; r < 4; ++r) {
                float dv = fmaf(-2.0f, acc[ti][r], c2v);
                if (dv < d1s[ti][r]) {
                    d2s[ti][r] = d1s[ti][r];
                    d1s[ti][r] = dv;
                    ids_[ti][r] = cbase;
                } else {
                    d2s[ti][r] = fminf(d2s[ti][r], dv);
                }
            }
        buf ^= 1;
    }

    if (wc == 0 && l4 == 0) {
#pragma unroll
        for (int ti = 0; ti < 2; ++ti)
            x2s[wr * 32 + ti * 16 + l15] = px2[ti];
    }

    // merge: 4 xor-shuffle stages over l15 (codes), then across wc via LDS
    __syncthreads();                     // loop done; Bh free for overlay
    float4* red = (float4*)&Bh[0][0];
#pragma unroll
    for (int ti = 0; ti < 2; ++ti)
#pragma unroll
        for (int r = 0; r < 4; ++r) {
            float d1 = d1s[ti][r], d2 = d2s[ti][r];
            int id = ids_[ti][r];
#pragma unroll
            for (int m = 1; m < 16; m <<= 1) {
                float od1 = __shfl_xor(d1, m);
                float od2 = __shfl_xor(d2, m);
                int oid = __shfl_xor(id, m);
                if (od1 < d1) { d2 = fminf(d1, od2); d1 = od1; id = oid; }
                else d2 = fminf(d2, fminf(od1, od2));
            }
            if (l15 == 0)
                red[wc * BM + wr * 32 + ti * 16 + l4 * 4 + r] =
                    make_float4(d1, __int_as_float(id), d2, 0.f);
        }
    __syncthreads();

    if (tid < BM) {
        float4 a = red[tid], c = red[BM + tid];
        float d1 = a.x, d2 = a.z;
        int id = __float_as_int(a.y);
        if (c.x < d1) { d2 = fminf(d1, c.z); d1 = c.x; id = __float_as_int(c.y); }
        else d2 = fminf(d2, fminf(c.x, c.z));
        int tok = tok0 + tid;
        int idx = tok * NG + g;
        int p = pad[tok];
        ws_ids[idx] = id;
        out_ids[idx] = p ? -1.0f : (float)id;
        lossg[idx] = p ? 0.0f : (d1 + x2s[tid]);
        idsL[tid] = p ? -1 : id;         // -1 encodes padded (zero row)
        if (!p && d2 - d1 < MARGIN) {
            int pos = atomicAdd(cnt, 1);
            flags[pos] = idx;
        }
    }
    __syncthreads();

    // fused gather: write quantized_st rows (64 tokens x 128 floats, this g)
#pragma unroll
    for (int it = 0; it < 8; ++it) {
        int i = it * 256 + tid;          // i in [0,2048)
        int tl = i >> 5, d4 = i & 31;
        int id = idsL[tl];
        float4 q = make_float4(0.f, 0.f, 0.f, 0.f);
        if (id >= 0)
            q = ((const float4*)(cb + ((size_t)id * NG + g) * ND))[d4];
        ((float4*)(out_q + ((size_t)(tok0 + tl) * NG + g) * ND))[d4] = q;
    }
}

// ---------------------------------------------------------------------------
// exact fp32 recheck, BLOCK per flag: R1-identical arithmetic; overwrites
// ids, lossg AND the quantized_st row for flagged (token,g).
// ---------------------------------------------------------------------------
__global__ __launch_bounds__(256) void recheck(
    const float* __restrict__ x, const int* __restrict__ pad,
    const float* __restrict__ cb, const float* __restrict__ c2w,
    const int* __restrict__ cnt, const int* __restrict__ flags,
    int* __restrict__ ws_ids, float* __restrict__ out_ids,
    float* __restrict__ out_q, float* __restrict__ lossg) {
    __shared__ __align__(16) float xs[ND];
    __shared__ float2 redw[4];
    __shared__ int bidS;
    const int tid = threadIdx.x;
    const int lane = tid & 63;
    const int w = tid >> 6;
    const int n_f = cnt[0];

    for (int f = blockIdx.x; f < n_f; f += gridDim.x) {
        int idx = flags[f];
        int g = idx & 7;
        __syncthreads();
        if (tid < 32)
            ((float4*)xs)[tid] = ((const float4*)(x + (size_t)idx * ND))[tid];
        __syncthreads();

        float rr[8];
#pragma unroll
        for (int j = 0; j < 8; ++j) rr[j] = 0.0f;
#pragma unroll
        for (int i = 0; i < 32; ++i) {
            float4 v = ((const float4*)xs)[i];
            int j0 = (i * 4) & 7;
            rr[j0 + 0] = __fadd_rn(rr[j0 + 0], __fmul_rn(v.x, v.x));
            rr[j0 + 1] = __fadd_rn(rr[j0 + 1], __fmul_rn(v.y, v.y));
            rr[j0 + 2] = __fadd_rn(rr[j0 + 2], __fmul_rn(v.z, v.z));
            rr[j0 + 3] = __fadd_rn(rr[j0 + 3], __fmul_rn(v.w, v.w));
        }
        float x2v = __fadd_rn(
            __fadd_rn(__fadd_rn(rr[0], rr[1]), __fadd_rn(rr[2], rr[3])),
            __fadd_rn(__fadd_rn(rr[4], rr[5]), __fadd_rn(rr[6], rr[7])));

        float best = INFINITY;
        int bid = 0x7FFFFFFF;
        float s0 = 0.f, s1 = 0.f, s2 = 0.f, s3 = 0.f;
#pragma unroll
        for (int i = 0; i < 32; ++i) {
            float4 a = ((const float4*)xs)[i];
            float4 q0 = ((const float4*)(cb + ((size_t)(tid) * NG + g) * ND))[i];
            float4 q1 = ((const float4*)(cb + ((size_t)(tid + 256) * NG + g) * ND))[i];
            float4 q2 = ((const float4*)(cb + ((size_t)(tid + 512) * NG + g) * ND))[i];
            float4 q3 = ((const float4*)(cb + ((size_t)(tid + 768) * NG + g) * ND))[i];
            s0 = fmaf(a.x, q0.x, s0); s0 = fmaf(a.y, q0.y, s0);
            s0 = fmaf(a.z, q0.z, s0); s0 = fmaf(a.w, q0.w, s0);
            s1 = fmaf(a.x, q1.x, s1); s1 = fmaf(a.y, q1.y, s1);
            s1 = fmaf(a.z, q1.z, s1); s1 = fmaf(a.w, q1.w, s1);
            s2 = fmaf(a.x, q2.x, s2); s2 = fmaf(a.y, q2.y, s2);
            s2 = fmaf(a.z, q2.z, s2); s2 = fmaf(a.w, q2.w, s2);
            s3 = fmaf(a.x, q3.x, s3); s3 = fmaf(a.y, q3.y, s3);
            s3 = fmaf(a.z, q3.z, s3); s3 = fmaf(a.w, q3.w, s3);
        }
        float dd[4] = {s0, s1, s2, s3};
#pragma unroll
        for (int jj = 0; jj < 4; ++jj) {
            int c = tid + 256 * jj;
            float d = __fadd_rn(__fsub_rn(x2v, __fmul_rn(2.0f, dd[jj])),
                                c2w[(size_t)c * NG + g]);
            if (d < best || (d == best && c < bid)) { best = d; bid = c; }
        }
#pragma unroll
        for (int m = 1; m < 64; m <<= 1) {
            float od = __shfl_xor(best, m);
            int ob = __shfl_xor(bid, m);
            if (od < best || (od == best && ob < bid)) { best = od; bid = ob; }
        }
        if (lane == 0) redw[w] = make_float2(best, __int_as_float(bid));
        __syncthreads();
        if (tid == 0) {
            float b2 = redw[0].x;
            int i2 = __float_as_int(redw[0].y);
#pragma unroll
            for (int ww = 1; ww < 4; ++ww) {
                float ob = redw[ww].x;
                int oi = __float_as_int(redw[ww].y);
                if (ob < b2 || (ob == b2 && oi < i2)) { b2 = ob; i2 = oi; }
            }
            ws_ids[idx] = i2;
            out_ids[idx] = (float)i2;    // flagged tokens are never padded
            lossg[idx] = b2;
            bidS = i2;
        }
        __syncthreads();
        if (tid < 32) {
            float4 q = ((const float4*)(cb + ((size_t)bidS * NG + g) * ND))[tid];
            ((float4*)(out_q + (size_t)idx * ND))[tid] = q;
        }
    }
}

// ---------------------------------------------------------------------------
// loss stage 1: 64 blocks x 256 thr, one float4/thread, fixed-order tree
// ---------------------------------------------------------------------------
__global__ __launch_bounds__(256) void loss_part(
    const float* __restrict__ lossg, float* __restrict__ part) {
    __shared__ float sr[256];
    const int tid = threadIdx.x;
    float4 v = ((const float4*)lossg)[blockIdx.x * 256 + tid];
    sr[tid] = ((v.x + v.y) + (v.z + v.w));
    __syncthreads();
    for (int st = 128; st > 0; st >>= 1) {
        if (tid < st) sr[tid] += sr[tid + st];
        __syncthreads();
    }
    if (tid == 0) part[blockIdx.x] = sr[0];
}

// ---------------------------------------------------------------------------
// loss stage 2: deterministic final (64 partials + pad count)
// ---------------------------------------------------------------------------
__global__ __launch_bounds__(256) void final_kernel(
    const int* __restrict__ pad, const float* __restrict__ part,
    float* __restrict__ out_l) {
    __shared__ int mr[256];
    const int tid = threadIdx.x;
    int m = 0;
#pragma unroll
    for (int i = 0; i < 32; ++i) m += 1 - pad[tid * 32 + i];
    mr[tid] = m;
    __syncthreads();
    for (int st = 128; st > 0; st >>= 1) {
        if (tid < st) mr[tid] += mr[tid + st];
        __syncthreads();
    }
    if (tid == 0) {
        float s = 0.f;
#pragma unroll
        for (int i = 0; i < 64; ++i) s += part[i];
        float k = s / (float)mr[0];
        out_l[0] = k;
        out_l[1] = k;
        out_l[2] = k + k;
    }
}

// ---------------------------------------------------------------------------
extern "C" void kernel_launch(void* const* d_in, const int* in_sizes, int n_in,
                              void* d_out, int out_size, void* d_ws, size_t ws_size,
                              hipStream_t stream) {
    const float* x = (const float*)d_in[0];
    const int* pad = (const int*)d_in[1];
    const float* cb = (const float*)d_in[2];
    float* out = (float*)d_out;
    float* ws = (float*)d_ws;

    float* ws_c2a = ws + OFF_C2A;
    float* ws_c2b = ws + OFF_C2B;
    int* ws_ids = (int*)(ws + OFF_IDS);
    float* ws_lossg = ws + OFF_LOSSG;
    int* ws_cnt = (int*)(ws + OFF_CNT);
    int* ws_flags = (int*)(ws + OFF_FLAGS);
    f16* cbh = (f16*)(ws + OFF_CBH);
    float* ws_part = ws + OFF_PART;

    prep_kernel<<<NV * NG / 256, 256, 0, stream>>>(cb, cbh, ws_c2a, ws_c2b,
                                                   ws_cnt);
    mfma_gemm<<<(BT / BM) * NG, 256, 0, stream>>>(x, cbh, cb, ws_c2b, pad,
                                                  ws_ids, out + OUT_IDS,
                                                  out + OUT_Q, ws_lossg,
                                                  ws_cnt, ws_flags);
    recheck<<<2048, 256, 0, stream>>>(x, pad, cb, ws_c2a, ws_cnt, ws_flags,
                                      ws_ids, out + OUT_IDS, out + OUT_Q,
                                      ws_lossg);
    loss_part<<<64, 256, 0, stream>>>(ws_lossg, ws_part);
    final_kernel<<<1, 256, 0, stream>>>(pad, ws_part, out + OUT_L);
}

// Round 15
// 98.933 us; speedup vs baseline: 1.7830x; 1.0648x over previous
//
#include <hip/hip_runtime.h>
#include <math.h>

typedef _Float16 f16;
typedef f16 half8 __attribute__((ext_vector_type(8)));
typedef float f32x4 __attribute__((ext_vector_type(4)));

// Problem sizes: B=4, T=2048, G=8, D=128, V=1024
#define BT 8192
#define NG 8
#define ND 128
#define NV 1024
#define MARGIN 0.08f     // 1-term fp16 dist err sigma ~4.5e-3 -> 18 sigma
#define BM 64            // tokens per block
#define BN 32            // codes per tile
#define NT 32            // code tiles

// d_out layout (float32): ids[65536] | quantized_st[8388608] | 3 losses
#define OUT_IDS 0
#define OUT_Q   65536
#define OUT_L   (65536 + 8388608)

// ws float offsets (~1.9 MB)
#define OFF_C2A   0                  // c2 [v*8+g] (recheck)        (8192)
#define OFF_C2B   8192               // c2 [g*NV+v] (gemm)          (8192)
#define OFF_LOSSG 81920              // per-(token,g) loss partial  (65536)
#define OFF_CNT   147456             // flag count                  (8)
#define OFF_FLAGS 147464             // flag list                   (65536)
#define OFF_CBH   213000             // cbh fp16 swizzled stream    (262144 fl)
#define OFF_PART  (OFF_CBH + 262144) // loss partials               (64)

// ---------------------------------------------------------------------------
// async global->LDS, 16B per lane (linear dest, pre-swizzled source)
// ---------------------------------------------------------------------------
__device__ __forceinline__ void gll16(const f16* g, f16* l) {
    __builtin_amdgcn_global_load_lds(
        (const __attribute__((address_space(1))) unsigned int*)g,
        (__attribute__((address_space(3))) unsigned int*)l, 16, 0, 0);
}

// ---------------------------------------------------------------------------
// prep, 16-threads-per-row (512 blocks): fp16 convert + pre-swizzled store
// per thread; c2 via LDS partial products combined in the EXACT R1 chain
// order (t-ascending fadd per accumulator j, then pairwise-8) -> bitwise
// identical c2 to all previous passing rounds.
// ---------------------------------------------------------------------------
__global__ __launch_bounds__(256) void prep_kernel(
    const float* __restrict__ cb, f16* __restrict__ cbh,
    float* __restrict__ c2a, float* __restrict__ c2b, int* __restrict__ cnt) {
    __shared__ float prod[16][16][9];   // [row][t][j], pad 9 (bank spread)
    __shared__ float rbuf[16][8];
    const int tid = threadIdx.x;
    const int rloc = tid >> 4, t = tid & 15;
    const int idx = blockIdx.x * 16 + rloc;   // row = v*8+g
    if (blockIdx.x == 0 && tid == 0) *cnt = 0;
    const int v = idx >> 3, g = idx & 7;
    const int rl = v & 31;
    const float4* row4 = (const float4*)(cb + (size_t)idx * ND);

    float4 a = row4[t * 2], b = row4[t * 2 + 1];
    float vv[8] = {a.x, a.y, a.z, a.w, b.x, b.y, b.z, b.w};
    half8 h;
#pragma unroll
    for (int e = 0; e < 8; ++e) {
        prod[rloc][t][e] = __fmul_rn(vv[e], vv[e]);
        h[e] = (f16)vv[e];
    }
    int cn = v >> 5;
    size_t base = ((size_t)(g * 32 + cn)) * 4096 + rl * 128;
    *(half8*)(cbh + base + ((t ^ (rl & 7)) * 8)) = h;   // j = t ^ (rl&7)
    __syncthreads();

    if (t < 8) {    // accumulator j = t: exact R1 chain (tt ascending)
        float r = 0.f;
#pragma unroll
        for (int tt = 0; tt < 16; ++tt)
            r = __fadd_rn(r, prod[rloc][tt][t]);
        rbuf[rloc][t] = r;
    }
    __syncthreads();
    if (t == 0) {
        float s = __fadd_rn(
            __fadd_rn(__fadd_rn(rbuf[rloc][0], rbuf[rloc][1]),
                      __fadd_rn(rbuf[rloc][2], rbuf[rloc][3])),
            __fadd_rn(__fadd_rn(rbuf[rloc][4], rbuf[rloc][5]),
                      __fadd_rn(rbuf[rloc][6], rbuf[rloc][7])));
        c2a[idx] = s;
        c2b[g * NV + v] = s;
    }
}

// ---------------------------------------------------------------------------
// MFMA distance GEMM, pure-fp16, TRIPLE-buffered depth-2 prefetch.
// Block = 64 tokens x one g; 4 waves = 2 token-halves x 2 code-halves.
// Per-tile schedule:
//   s_waitcnt vmcnt(2)   [drains tile t; tile t+1 stays IN FLIGHT]
//   s_barrier + sched_barrier(0)
//   issue tile t+2 DMA   [2 tile-periods to fly]
//   compute tile t
// (last iter uses vmcnt(0): its own loads are the newest 2.)
// d' = c2 - 2*(xh.ch); exact per-thread running top-2; flag iff
// d2-d1 < MARGIN (18 sigma) -> exact recheck (sound). lossg = d1+x2 fused.
// Tail: quantized_st rows written here (fused gather).
// ---------------------------------------------------------------------------
__global__ __launch_bounds__(256, 4) void mfma_gemm(
    const float* __restrict__ x, const f16* __restrict__ cbh,
    const float* __restrict__ cb, const float* __restrict__ c2b,
    const int* __restrict__ pad, float* __restrict__ out_ids,
    float* __restrict__ out_q, float* __restrict__ lossg,
    int* __restrict__ cnt, int* __restrict__ flags) {
    __shared__ __align__(16) f16 Bh[3][BN * ND];   // 3 x 8 KB
    __shared__ __align__(16) float c2s[NV];        // 4 KB
    __shared__ float x2s[BM];                      // 256 B
    __shared__ int idsL[BM];                       // 256 B

    const int tid = threadIdx.x;
    const int b = blockIdx.x;
    const int g = b & 7;
    const int tok0 = (b >> 3) * BM;
    const int lane = tid & 63;
    const int w = tid >> 6;
    const int wr = w & 1, wc = w >> 1;
    const int l15 = lane & 15, l4 = lane >> 4;
    const int rw = wc * 16 + l15;            // code row in tile [0,32)

    // prologue: c2 -> LDS, issue tiles 0 and 1, A load/convert under them
    ((float4*)c2s)[tid] = ((const float4*)(c2b + (size_t)g * NV))[tid];
    {
        const f16* sh = cbh + ((size_t)(g * 32 + 0)) * 4096;
        gll16(sh + tid * 8, &Bh[0][tid * 8]);
        gll16(sh + 2048 + tid * 8, &Bh[0][2048 + tid * 8]);
        const f16* sh1 = cbh + ((size_t)(g * 32 + 1)) * 4096;
        gll16(sh1 + tid * 8, &Bh[1][tid * 8]);
        gll16(sh1 + 2048 + tid * 8, &Bh[1][2048 + tid * 8]);
    }

    half8 ah[4][2];   // [kk][ti]
    float px2[2] = {0.f, 0.f};
#pragma unroll
    for (int kk = 0; kk < 4; ++kk)
#pragma unroll
        for (int ti = 0; ti < 2; ++ti) {
            const float* ap = x + ((size_t)(tok0 + wr * 32 + ti * 16 + l15) * NG + g) * ND
                              + kk * 32 + l4 * 8;
            float4 p0 = *(const float4*)ap, p1 = *(const float4*)(ap + 4);
            float vv[8] = {p0.x, p0.y, p0.z, p0.w, p1.x, p1.y, p1.z, p1.w};
            half8 h;
#pragma unroll
            for (int j = 0; j < 8; ++j) {
                h[j] = (f16)vv[j];
                px2[ti] = fmaf(vv[j], vv[j], px2[ti]);
            }
            ah[kk][ti] = h;
        }
#pragma unroll
    for (int ti = 0; ti < 2; ++ti) {
        px2[ti] += __shfl_xor(px2[ti], 16);
        px2[ti] += __shfl_xor(px2[ti], 32);
    }

    float d1s[2][4], d2s[2][4];
    int ids_[2][4];
#pragma unroll
    for (int ti = 0; ti < 2; ++ti)
#pragma unroll
        for (int r = 0; r < 4; ++r) {
            d1s[ti][r] = INFINITY;
            d2s[ti][r] = INFINITY;
            ids_[ti][r] = 0;
        }

    int buf = 0;   // tile t lives in buffer t % 3
#pragma unroll 1
    for (int t = 0; t < NT; ++t) {
        // drain tile t only; tile t+1 stays in flight (depth-2 pipeline)
        if (t + 1 < NT)
            asm volatile("s_waitcnt vmcnt(2) lgkmcnt(0)" ::: "memory");
        else
            asm volatile("s_waitcnt vmcnt(0) lgkmcnt(0)" ::: "memory");
        __builtin_amdgcn_s_barrier();
        __builtin_amdgcn_sched_barrier(0);

        // issue tile t+2 into buffer (t+2)%3 (had 2 periods to fly)
        if (t + 2 < NT) {
            int nb = buf + 2;
            nb = (nb >= 3) ? nb - 3 : nb;
            const f16* sh = cbh + ((size_t)(g * 32 + t + 2)) * 4096;
            gll16(sh + tid * 8, &Bh[nb][tid * 8]);
            gll16(sh + 2048 + tid * 8, &Bh[nb][2048 + tid * 8]);
        }

        const int cbase = t * BN + rw;
        f32x4 acc[2];
#pragma unroll
        for (int ti = 0; ti < 2; ++ti) acc[ti] = (f32x4){0.f, 0.f, 0.f, 0.f};

#pragma unroll
        for (int kk = 0; kk < 4; ++kk) {
            int off = rw * 128 + (((kk * 4 + l4) ^ (rw & 7)) << 3);
            half8 bh = *(const half8*)(&Bh[buf][off]);
#pragma unroll
            for (int ti = 0; ti < 2; ++ti)
                acc[ti] = __builtin_amdgcn_mfma_f32_16x16x32_f16(
                    ah[kk][ti], bh, acc[ti], 0, 0, 0);
        }

        float c2v = c2s[cbase];
#pragma unroll
        for (int ti = 0; ti < 2; ++ti)
#pragma unroll
            for (int r = 0; r < 4; ++r) {
                float dv = fmaf(-2.0f, acc[ti][r], c2v);
                if (dv < d1s[ti][r]) {
                    d2s[ti][r] = d1s[ti][r];
                    d1s[ti][r] = dv;
                    ids_[ti][r] = cbase;
                } else {
                    d2s[ti][r] = fminf(d2s[ti][r], dv);
                }
            }
        buf = (buf == 2) ? 0 : buf + 1;
    }

    if (wc == 0 && l4 == 0) {
#pragma unroll
        for (int ti = 0; ti < 2; ++ti)
            x2s[wr * 32 + ti * 16 + l15] = px2[ti];
    }

    // merge: 4 xor-shuffle stages over l15 (codes), then across wc via LDS
    __syncthreads();                     // loop done; Bh free for overlay
    float4* red = (float4*)&Bh[0][0];
#pragma unroll
    for (int ti = 0; ti < 2; ++ti)
#pragma unroll
        for (int r = 0; r < 4; ++r) {
            float d1 = d1s[ti][r], d2 = d2s[ti][r];
            int id = ids_[ti][r];
#pragma unroll
            for (int m = 1; m < 16; m <<= 1) {
                float od1 = __shfl_xor(d1, m);
                float od2 = __shfl_xor(d2, m);
                int oid = __shfl_xor(id, m);
                if (od1 < d1) { d2 = fminf(d1, od2); d1 = od1; id = oid; }
                else d2 = fminf(d2, fminf(od1, od2));
            }
            if (l15 == 0)
                red[wc * BM + wr * 32 + ti * 16 + l4 * 4 + r] =
                    make_float4(d1, __int_as_float(id), d2, 0.f);
        }
    __syncthreads();

    if (tid < BM) {
        float4 a = red[tid], c = red[BM + tid];
        float d1 = a.x, d2 = a.z;
        int id = __float_as_int(a.y);
        if (c.x < d1) { d2 = fminf(d1, c.z); d1 = c.x; id = __float_as_int(c.y); }
        else d2 = fminf(d2, fminf(c.x, c.z));
        int tok = tok0 + tid;
        int idx = tok * NG + g;
        int p = pad[tok];
        out_ids[idx] = p ? -1.0f : (float)id;
        lossg[idx] = p ? 0.0f : (d1 + x2s[tid]);
        idsL[tid] = p ? -1 : id;         // -1 encodes padded (zero row)
        if (!p && d2 - d1 < MARGIN) {
            int pos = atomicAdd(cnt, 1);
            flags[pos] = idx;
        }
    }
    __syncthreads();

    // fused gather: write quantized_st rows (64 tokens x 128 floats, this g)
#pragma unroll
    for (int it = 0; it < 8; ++it) {
        int i = it * 256 + tid;          // i in [0,2048)
        int tl = i >> 5, d4 = i & 31;
        int id = idsL[tl];
        float4 q = make_float4(0.f, 0.f, 0.f, 0.f);
        if (id >= 0)
            q = ((const float4*)(cb + ((size_t)id * NG + g) * ND))[d4];
        ((float4*)(out_q + ((size_t)(tok0 + tl) * NG + g) * ND))[d4] = q;
    }
}

// ---------------------------------------------------------------------------
// exact fp32 recheck, BLOCK per flag: R1-identical arithmetic; overwrites
// ids, lossg AND the quantized_st row for flagged (token,g).
// ---------------------------------------------------------------------------
__global__ __launch_bounds__(256) void recheck(
    const float* __restrict__ x, const int* __restrict__ pad,
    const float* __restrict__ cb, const float* __restrict__ c2w,
    const int* __restrict__ cnt, const int* __restrict__ flags,
    float* __restrict__ out_ids, float* __restrict__ out_q,
    float* __restrict__ lossg) {
    __shared__ __align__(16) float xs[ND];
    __shared__ float2 redw[4];
    __shared__ int bidS;
    const int tid = threadIdx.x;
    const int lane = tid & 63;
    const int w = tid >> 6;
    const int n_f = cnt[0];

    for (int f = blockIdx.x; f < n_f; f += gridDim.x) {
        int idx = flags[f];
        int g = idx & 7;
        __syncthreads();
        if (tid < 32)
            ((float4*)xs)[tid] = ((const float4*)(x + (size_t)idx * ND))[tid];
        __syncthreads();

        float rr[8];
#pragma unroll
        for (int j = 0; j < 8; ++j) rr[j] = 0.0f;
#pragma unroll
        for (int i = 0; i < 32; ++i) {
            float4 v = ((const float4*)xs)[i];
            int j0 = (i * 4) & 7;
            rr[j0 + 0] = __fadd_rn(rr[j0 + 0], __fmul_rn(v.x, v.x));
            rr[j0 + 1] = __fadd_rn(rr[j0 + 1], __fmul_rn(v.y, v.y));
            rr[j0 + 2] = __fadd_rn(rr[j0 + 2], __fmul_rn(v.z, v.z));
            rr[j0 + 3] = __fadd_rn(rr[j0 + 3], __fmul_rn(v.w, v.w));
        }
        float x2v = __fadd_rn(
            __fadd_rn(__fadd_rn(rr[0], rr[1]), __fadd_rn(rr[2], rr[3])),
            __fadd_rn(__fadd_rn(rr[4], rr[5]), __fadd_rn(rr[6], rr[7])));

        float best = INFINITY;
        int bid = 0x7FFFFFFF;
        float s0 = 0.f, s1 = 0.f, s2 = 0.f, s3 = 0.f;
#pragma unroll
        for (int i = 0; i < 32; ++i) {
            float4 a = ((const float4*)xs)[i];
            float4 q0 = ((const float4*)(cb + ((size_t)(tid) * NG + g) * ND))[i];
            float4 q1 = ((const float4*)(cb + ((size_t)(tid + 256) * NG + g) * ND))[i];
            float4 q2 = ((const float4*)(cb + ((size_t)(tid + 512) * NG + g) * ND))[i];
            float4 q3 = ((const float4*)(cb + ((size_t)(tid + 768) * NG + g) * ND))[i];
            s0 = fmaf(a.x, q0.x, s0); s0 = fmaf(a.y, q0.y, s0);
            s0 = fmaf(a.z, q0.z, s0); s0 = fmaf(a.w, q0.w, s0);
            s1 = fmaf(a.x, q1.x, s1); s1 = fmaf(a.y, q1.y, s1);
            s1 = fmaf(a.z, q1.z, s1); s1 = fmaf(a.w, q1.w, s1);
            s2 = fmaf(a.x, q2.x, s2); s2 = fmaf(a.y, q2.y, s2);
            s2 = fmaf(a.z, q2.z, s2); s2 = fmaf(a.w, q2.w, s2);
            s3 = fmaf(a.x, q3.x, s3); s3 = fmaf(a.y, q3.y, s3);
            s3 = fmaf(a.z, q3.z, s3); s3 = fmaf(a.w, q3.w, s3);
        }
        float dd[4] = {s0, s1, s2, s3};
#pragma unroll
        for (int jj = 0; jj < 4; ++jj) {
            int c = tid + 256 * jj;
            float d = __fadd_rn(__fsub_rn(x2v, __fmul_rn(2.0f, dd[jj])),
                                c2w[(size_t)c * NG + g]);
            if (d < best || (d == best && c < bid)) { best = d; bid = c; }
        }
#pragma unroll
        for (int m = 1; m < 64; m <<= 1) {
            float od = __shfl_xor(best, m);
            int ob = __shfl_xor(bid, m);
            if (od < best || (od == best && ob < bid)) { best = od; bid = ob; }
        }
        if (lane == 0) redw[w] = make_float2(best, __int_as_float(bid));
        __syncthreads();
        if (tid == 0) {
            float b2 = redw[0].x;
            int i2 = __float_as_int(redw[0].y);
#pragma unroll
            for (int ww = 1; ww < 4; ++ww) {
                float ob = redw[ww].x;
                int oi = __float_as_int(redw[ww].y);
                if (ob < b2 || (ob == b2 && oi < i2)) { b2 = ob; i2 = oi; }
            }
            out_ids[idx] = (float)i2;    // flagged tokens are never padded
            lossg[idx] = b2;
            bidS = i2;
        }
        __syncthreads();
        if (tid < 32) {
            float4 q = ((const float4*)(cb + ((size_t)bidS * NG + g) * ND))[tid];
            ((float4*)(out_q + (size_t)idx * ND))[tid] = q;
        }
    }
}

// ---------------------------------------------------------------------------
// loss stage 1: 64 blocks x 256 thr, one float4/thread, fixed-order tree
// ---------------------------------------------------------------------------
__global__ __launch_bounds__(256) void loss_part(
    const float* __restrict__ lossg, float* __restrict__ part) {
    __shared__ float sr[256];
    const int tid = threadIdx.x;
    float4 v = ((const float4*)lossg)[blockIdx.x * 256 + tid];
    sr[tid] = ((v.x + v.y) + (v.z + v.w));
    __syncthreads();
    for (int st = 128; st > 0; st >>= 1) {
        if (tid < st) sr[tid] += sr[tid + st];
        __syncthreads();
    }
    if (tid == 0) part[blockIdx.x] = sr[0];
}

// ---------------------------------------------------------------------------
// loss stage 2: deterministic final (64 partials + pad count)
// ---------------------------------------------------------------------------
__global__ __launch_bounds__(256) void final_kernel(
    const int* __restrict__ pad, const float* __restrict__ part,
    float* __restrict__ out_l) {
    __shared__ int mr[256];
    const int tid = threadIdx.x;
    int m = 0;
#pragma unroll
    for (int i = 0; i < 32; ++i) m += 1 - pad[tid * 32 + i];
    mr[tid] = m;
    __syncthreads();
    for (int st = 128; st > 0; st >>= 1) {
        if (tid < st) mr[tid] += mr[tid + st];
        __syncthreads();
    }
    if (tid == 0) {
        float s = 0.f;
#pragma unroll
        for (int i = 0; i < 64; ++i) s += part[i];
        float k = s / (float)mr[0];
        out_l[0] = k;
        out_l[1] = k;
        out_l[2] = k + k;
    }
}

// ---------------------------------------------------------------------------
extern "C" void kernel_launch(void* const* d_in, const int* in_sizes, int n_in,
                              void* d_out, int out_size, void* d_ws, size_t ws_size,
                              hipStream_t stream) {
    const float* x = (const float*)d_in[0];
    const int* pad = (const int*)d_in[1];
    const float* cb = (const float*)d_in[2];
    float* out = (float*)d_out;
    float* ws = (float*)d_ws;

    float* ws_c2a = ws + OFF_C2A;
    float* ws_c2b = ws + OFF_C2B;
    float* ws_lossg = ws + OFF_LOSSG;
    int* ws_cnt = (int*)(ws + OFF_CNT);
    int* ws_flags = (int*)(ws + OFF_FLAGS);
    f16* cbh = (f16*)(ws + OFF_CBH);
    float* ws_part = ws + OFF_PART;

    prep_kernel<<<NV * NG / 16, 256, 0, stream>>>(cb, cbh, ws_c2a, ws_c2b,
                                                  ws_cnt);
    mfma_gemm<<<(BT / BM) * NG, 256, 0, stream>>>(x, cbh, cb, ws_c2b, pad,
                                                  out + OUT_IDS, out + OUT_Q,
                                                  ws_lossg, ws_cnt, ws_flags);
    recheck<<<2048, 256, 0, stream>>>(x, pad, cb, ws_c2a, ws_cnt, ws_flags,
                                      out + OUT_IDS, out + OUT_Q, ws_lossg);
    loss_part<<<64, 256, 0, stream>>>(ws_lossg, ws_part);
    final_kernel<<<1, 256, 0, stream>>>(pad, ws_part, out + OUT_L);
}

// Round 16
// 97.489 us; speedup vs baseline: 1.8094x; 1.0148x over previous
//
#include <hip/hip_runtime.h>
#include <math.h>

typedef _Float16 f16;
typedef f16 half8 __attribute__((ext_vector_type(8)));
typedef float f32x4 __attribute__((ext_vector_type(4)));

// Problem sizes: B=4, T=2048, G=8, D=128, V=1024
#define BT 8192
#define NG 8
#define ND 128
#define NV 1024
#define MARGIN 0.08f     // 1-term fp16 dist err sigma ~4.5e-3 -> 18 sigma
#define BM 64            // tokens per block
#define BN 64            // codes per tile
#define NT 16            // code tiles

// d_out layout (float32): ids[65536] | quantized_st[8388608] | 3 losses
#define OUT_IDS 0
#define OUT_Q   65536
#define OUT_L   (65536 + 8388608)

// ws float offsets (~3 MB)
#define OFF_C2A   0                  // c2 [v*8+g] (recheck)        (8192)
#define OFF_C2B   8192               // c2 [g*NV+v] (gemm)          (8192)
#define OFF_LOSSG 81920              // per-(token,g) loss partial  (65536)
#define OFF_CNT   147456             // flag count                  (8)
#define OFF_FLAGS 147464             // flag list                   (65536)
#define OFF_CBH   213000             // cbh fp16 swizzled stream    (524288 fl)
#define OFF_PART  (OFF_CBH + 524288) // loss partials               (64)

// ---------------------------------------------------------------------------
// async global->LDS, 16B per lane (linear dest, pre-swizzled source)
// ---------------------------------------------------------------------------
__device__ __forceinline__ void gll16(const f16* g, f16* l) {
    __builtin_amdgcn_global_load_lds(
        (const __attribute__((address_space(1))) unsigned int*)g,
        (__attribute__((address_space(3))) unsigned int*)l, 16, 0, 0);
}

// ---------------------------------------------------------------------------
// prep, 16-threads-per-row (512 blocks): fp16 convert + pre-swizzled store;
// c2 via LDS partials combined in the EXACT R1 chain order. Chunks are now
// 64-row (BN=64): stream[(g*16+cn)*8192 + rl*128 + (j^(rl&7))*8 + e],
// cn = v>>6, rl = v&63.
// ---------------------------------------------------------------------------
__global__ __launch_bounds__(256) void prep_kernel(
    const float* __restrict__ cb, f16* __restrict__ cbh,
    float* __restrict__ c2a, float* __restrict__ c2b, int* __restrict__ cnt) {
    __shared__ float prod[16][16][9];
    __shared__ float rbuf[16][8];
    const int tid = threadIdx.x;
    const int rloc = tid >> 4, t = tid & 15;
    const int idx = blockIdx.x * 16 + rloc;   // row = v*8+g
    if (blockIdx.x == 0 && tid == 0) *cnt = 0;
    const int v = idx >> 3, g = idx & 7;
    const int rl = v & 63;
    const float4* row4 = (const float4*)(cb + (size_t)idx * ND);

    float4 a = row4[t * 2], b = row4[t * 2 + 1];
    float vv[8] = {a.x, a.y, a.z, a.w, b.x, b.y, b.z, b.w};
    half8 h;
#pragma unroll
    for (int e = 0; e < 8; ++e) {
        prod[rloc][t][e] = __fmul_rn(vv[e], vv[e]);
        h[e] = (f16)vv[e];
    }
    int cn = v >> 6;
    size_t base = ((size_t)(g * 16 + cn)) * 8192 + rl * 128;
    *(half8*)(cbh + base + ((t ^ (rl & 7)) * 8)) = h;
    __syncthreads();

    if (t < 8) {
        float r = 0.f;
#pragma unroll
        for (int tt = 0; tt < 16; ++tt)
            r = __fadd_rn(r, prod[rloc][tt][t]);
        rbuf[rloc][t] = r;
    }
    __syncthreads();
    if (t == 0) {
        float s = __fadd_rn(
            __fadd_rn(__fadd_rn(rbuf[rloc][0], rbuf[rloc][1]),
                      __fadd_rn(rbuf[rloc][2], rbuf[rloc][3])),
            __fadd_rn(__fadd_rn(rbuf[rloc][4], rbuf[rloc][5]),
                      __fadd_rn(rbuf[rloc][6], rbuf[rloc][7])));
        c2a[idx] = s;
        c2b[g * NV + v] = s;
    }
}

// ---------------------------------------------------------------------------
// MFMA distance GEMM, pure-fp16, BN=64 (16 tiles), depth-1 dbuf with the
// R13-measured-best sync:
//   s_waitcnt vmcnt(0) lgkmcnt(0); s_barrier; sched_barrier(0);
//   issue tile t+1; compute tile t.
// Per thread per tile: 16 dist elems (2 ti x 2 tj x 4 r); running exact
// top-2; flag iff d2-d1 < MARGIN -> exact recheck (sound).
// Tail: fused gather writes quantized_st AND computes lossg exactly
// (sum (q-x)^2, R1-proven form) -> x2 machinery deleted.
// ---------------------------------------------------------------------------
__global__ __launch_bounds__(256, 4) void mfma_gemm(
    const float* __restrict__ x, const f16* __restrict__ cbh,
    const float* __restrict__ cb, const float* __restrict__ c2b,
    const int* __restrict__ pad, float* __restrict__ out_ids,
    float* __restrict__ out_q, float* __restrict__ lossg,
    int* __restrict__ cnt, int* __restrict__ flags) {
    __shared__ __align__(16) f16 Bh[2][BN * ND];   // 2 x 16 KB
    __shared__ __align__(16) float c2s[NV];        // 4 KB
    __shared__ int idsL[BM];                       // 256 B

    const int tid = threadIdx.x;
    const int b = blockIdx.x;
    const int g = b & 7;
    const int tok0 = (b >> 3) * BM;
    const int lane = tid & 63;
    const int w = tid >> 6;
    const int wr = w & 1, wc = w >> 1;
    const int l15 = lane & 15, l4 = lane >> 4;

    // prologue: c2 -> LDS, issue tile-0 DMA, A load/convert under it
    ((float4*)c2s)[tid] = ((const float4*)(c2b + (size_t)g * NV))[tid];
    {
        const f16* sh = cbh + ((size_t)(g * 16 + 0)) * 8192;
#pragma unroll
        for (int it = 0; it < 4; ++it)
            gll16(sh + it * 2048 + tid * 8, &Bh[0][it * 2048 + tid * 8]);
    }

    half8 ah[4][2];   // [kk][ti]
#pragma unroll
    for (int kk = 0; kk < 4; ++kk)
#pragma unroll
        for (int ti = 0; ti < 2; ++ti) {
            const float* ap = x + ((size_t)(tok0 + wr * 32 + ti * 16 + l15) * NG + g) * ND
                              + kk * 32 + l4 * 8;
            float4 p0 = *(const float4*)ap, p1 = *(const float4*)(ap + 4);
            float vv[8] = {p0.x, p0.y, p0.z, p0.w, p1.x, p1.y, p1.z, p1.w};
            half8 h;
#pragma unroll
            for (int j = 0; j < 8; ++j) h[j] = (f16)vv[j];
            ah[kk][ti] = h;
        }

    float d1s[2][4], d2s[2][4];
    int ids_[2][4];
#pragma unroll
    for (int ti = 0; ti < 2; ++ti)
#pragma unroll
        for (int r = 0; r < 4; ++r) {
            d1s[ti][r] = INFINITY;
            d2s[ti][r] = INFINITY;
            ids_[ti][r] = 0;
        }

    int buf = 0;
#pragma unroll 1
    for (int t = 0; t < NT; ++t) {
        // tile t's loads had all of tile t-1's compute to fly
        asm volatile("s_waitcnt vmcnt(0) lgkmcnt(0)" ::: "memory");
        __builtin_amdgcn_s_barrier();
        __builtin_amdgcn_sched_barrier(0);

        // issue tile t+1 (flies under compute of tile t)
        if (t + 1 < NT) {
            const f16* sh = cbh + ((size_t)(g * 16 + t + 1)) * 8192;
#pragma unroll
            for (int it = 0; it < 4; ++it)
                gll16(sh + it * 2048 + tid * 8,
                      &Bh[buf ^ 1][it * 2048 + tid * 8]);
        }

        f32x4 acc[2][2];
#pragma unroll
        for (int ti = 0; ti < 2; ++ti)
#pragma unroll
            for (int tj = 0; tj < 2; ++tj)
                acc[ti][tj] = (f32x4){0.f, 0.f, 0.f, 0.f};

#pragma unroll
        for (int kk = 0; kk < 4; ++kk) {
            half8 bh[2];
#pragma unroll
            for (int tj = 0; tj < 2; ++tj) {
                int rw = wc * 32 + tj * 16 + l15;
                bh[tj] = *(const half8*)(
                    &Bh[buf][rw * 128 + (((kk * 4 + l4) ^ (rw & 7)) << 3)]);
            }
#pragma unroll
            for (int ti = 0; ti < 2; ++ti)
#pragma unroll
                for (int tj = 0; tj < 2; ++tj)
                    acc[ti][tj] = __builtin_amdgcn_mfma_f32_16x16x32_f16(
                        ah[kk][ti], bh[tj], acc[ti][tj], 0, 0, 0);
        }

        // epilogue: d' = c2 - 2s; per-thread running exact top-2 (16 elems)
#pragma unroll
        for (int tj = 0; tj < 2; ++tj) {
            int code = t * BN + wc * 32 + tj * 16 + l15;
            float c2v = c2s[code];
#pragma unroll
            for (int ti = 0; ti < 2; ++ti)
#pragma unroll
                for (int r = 0; r < 4; ++r) {
                    float dv = fmaf(-2.0f, acc[ti][tj][r], c2v);
                    d2s[ti][r] = fminf(d2s[ti][r], fmaxf(d1s[ti][r], dv));
                    bool cless = dv < d1s[ti][r];
                    d1s[ti][r] = fminf(d1s[ti][r], dv);
                    ids_[ti][r] = cless ? code : ids_[ti][r];
                }
        }
        buf ^= 1;
    }

    // merge: 4 xor-shuffle stages over l15 (codes), then across wc via LDS
    __syncthreads();
    float4* red = (float4*)&Bh[0][0];
#pragma unroll
    for (int ti = 0; ti < 2; ++ti)
#pragma unroll
        for (int r = 0; r < 4; ++r) {
            float d1 = d1s[ti][r], d2 = d2s[ti][r];
            int id = ids_[ti][r];
#pragma unroll
            for (int m = 1; m < 16; m <<= 1) {
                float od1 = __shfl_xor(d1, m);
                float od2 = __shfl_xor(d2, m);
                int oid = __shfl_xor(id, m);
                if (od1 < d1) { d2 = fminf(d1, od2); d1 = od1; id = oid; }
                else d2 = fminf(d2, fminf(od1, od2));
            }
            if (l15 == 0)
                red[wc * BM + wr * 32 + ti * 16 + l4 * 4 + r] =
                    make_float4(d1, __int_as_float(id), d2, 0.f);
        }
    __syncthreads();

    if (tid < BM) {
        float4 a = red[tid], c = red[BM + tid];
        float d1 = a.x, d2 = a.z;
        int id = __float_as_int(a.y);
        if (c.x < d1) { d2 = fminf(d1, c.z); d1 = c.x; id = __float_as_int(c.y); }
        else d2 = fminf(d2, fminf(c.x, c.z));
        int tok = tok0 + tid;
        int idx = tok * NG + g;
        int p = pad[tok];
        out_ids[idx] = p ? -1.0f : (float)id;
        idsL[tid] = p ? -1 : id;
        if (!p && d2 - d1 < MARGIN) {
            int pos = atomicAdd(cnt, 1);
            flags[pos] = idx;
        }
    }
    __syncthreads();

    // fused gather + EXACT loss: 64 tokens x 32 float4 per g; each row's 32
    // threads sit in one half-wave -> shfl_xor(<=16) reduce, d4==0 writes.
#pragma unroll
    for (int it = 0; it < 8; ++it) {
        int i = it * 256 + tid;          // [0,2048)
        int tl = i >> 5, d4 = i & 31;
        int id = idsL[tl];
        float4 q = make_float4(0.f, 0.f, 0.f, 0.f);
        float s = 0.f;
        size_t rowo = ((size_t)(tok0 + tl) * NG + g) * ND;
        if (id >= 0) {
            q = ((const float4*)(cb + ((size_t)id * NG + g) * ND))[d4];
            float4 a = ((const float4*)(x + rowo))[d4];
            float e0 = q.x - a.x, e1 = q.y - a.y;
            float e2 = q.z - a.z, e3 = q.w - a.w;
            s = e0 * e0 + e1 * e1 + e2 * e2 + e3 * e3;
        }
        ((float4*)(out_q + rowo))[d4] = q;
#pragma unroll
        for (int m = 1; m < 32; m <<= 1) s += __shfl_xor(s, m);
        if (d4 == 0) lossg[(tok0 + tl) * NG + g] = (id >= 0) ? s : 0.0f;
    }
}

// ---------------------------------------------------------------------------
// exact fp32 recheck, BLOCK per flag: R1-identical arithmetic; overwrites
// ids, quantized_st row, and lossg (gather-form) for flagged (token,g).
// ---------------------------------------------------------------------------
__global__ __launch_bounds__(256) void recheck(
    const float* __restrict__ x, const int* __restrict__ pad,
    const float* __restrict__ cb, const float* __restrict__ c2w,
    const int* __restrict__ cnt, const int* __restrict__ flags,
    float* __restrict__ out_ids, float* __restrict__ out_q,
    float* __restrict__ lossg) {
    __shared__ __align__(16) float xs[ND];
    __shared__ float2 redw[4];
    __shared__ int bidS;
    const int tid = threadIdx.x;
    const int lane = tid & 63;
    const int w = tid >> 6;
    const int n_f = cnt[0];

    for (int f = blockIdx.x; f < n_f; f += gridDim.x) {
        int idx = flags[f];
        int g = idx & 7;
        __syncthreads();
        if (tid < 32)
            ((float4*)xs)[tid] = ((const float4*)(x + (size_t)idx * ND))[tid];
        __syncthreads();

        float rr[8];
#pragma unroll
        for (int j = 0; j < 8; ++j) rr[j] = 0.0f;
#pragma unroll
        for (int i = 0; i < 32; ++i) {
            float4 v = ((const float4*)xs)[i];
            int j0 = (i * 4) & 7;
            rr[j0 + 0] = __fadd_rn(rr[j0 + 0], __fmul_rn(v.x, v.x));
            rr[j0 + 1] = __fadd_rn(rr[j0 + 1], __fmul_rn(v.y, v.y));
            rr[j0 + 2] = __fadd_rn(rr[j0 + 2], __fmul_rn(v.z, v.z));
            rr[j0 + 3] = __fadd_rn(rr[j0 + 3], __fmul_rn(v.w, v.w));
        }
        float x2v = __fadd_rn(
            __fadd_rn(__fadd_rn(rr[0], rr[1]), __fadd_rn(rr[2], rr[3])),
            __fadd_rn(__fadd_rn(rr[4], rr[5]), __fadd_rn(rr[6], rr[7])));

        float best = INFINITY;
        int bid = 0x7FFFFFFF;
        float s0 = 0.f, s1 = 0.f, s2 = 0.f, s3 = 0.f;
#pragma unroll
        for (int i = 0; i < 32; ++i) {
            float4 a = ((const float4*)xs)[i];
            float4 q0 = ((const float4*)(cb + ((size_t)(tid) * NG + g) * ND))[i];
            float4 q1 = ((const float4*)(cb + ((size_t)(tid + 256) * NG + g) * ND))[i];
            float4 q2 = ((const float4*)(cb + ((size_t)(tid + 512) * NG + g) * ND))[i];
            float4 q3 = ((const float4*)(cb + ((size_t)(tid + 768) * NG + g) * ND))[i];
            s0 = fmaf(a.x, q0.x, s0); s0 = fmaf(a.y, q0.y, s0);
            s0 = fmaf(a.z, q0.z, s0); s0 = fmaf(a.w, q0.w, s0);
            s1 = fmaf(a.x, q1.x, s1); s1 = fmaf(a.y, q1.y, s1);
            s1 = fmaf(a.z, q1.z, s1); s1 = fmaf(a.w, q1.w, s1);
            s2 = fmaf(a.x, q2.x, s2); s2 = fmaf(a.y, q2.y, s2);
            s2 = fmaf(a.z, q2.z, s2); s2 = fmaf(a.w, q2.w, s2);
            s3 = fmaf(a.x, q3.x, s3); s3 = fmaf(a.y, q3.y, s3);
            s3 = fmaf(a.z, q3.z, s3); s3 = fmaf(a.w, q3.w, s3);
        }
        float dd[4] = {s0, s1, s2, s3};
#pragma unroll
        for (int jj = 0; jj < 4; ++jj) {
            int c = tid + 256 * jj;
            float d = __fadd_rn(__fsub_rn(x2v, __fmul_rn(2.0f, dd[jj])),
                                c2w[(size_t)c * NG + g]);
            if (d < best || (d == best && c < bid)) { best = d; bid = c; }
        }
#pragma unroll
        for (int m = 1; m < 64; m <<= 1) {
            float od = __shfl_xor(best, m);
            int ob = __shfl_xor(bid, m);
            if (od < best || (od == best && ob < bid)) { best = od; bid = ob; }
        }
        if (lane == 0) redw[w] = make_float2(best, __int_as_float(bid));
        __syncthreads();
        if (tid == 0) {
            float b2 = redw[0].x;
            int i2 = __float_as_int(redw[0].y);
#pragma unroll
            for (int ww = 1; ww < 4; ++ww) {
                float ob = redw[ww].x;
                int oi = __float_as_int(redw[ww].y);
                if (ob < b2 || (ob == b2 && oi < i2)) { b2 = ob; i2 = oi; }
            }
            out_ids[idx] = (float)i2;    // flagged tokens are never padded
            bidS = i2;
        }
        __syncthreads();
        if (tid < 32) {
            float4 q = ((const float4*)(cb + ((size_t)bidS * NG + g) * ND))[tid];
            ((float4*)(out_q + (size_t)idx * ND))[tid] = q;
            float4 a = ((const float4*)xs)[tid];
            float e0 = q.x - a.x, e1 = q.y - a.y;
            float e2 = q.z - a.z, e3 = q.w - a.w;
            float s = e0 * e0 + e1 * e1 + e2 * e2 + e3 * e3;
#pragma unroll
            for (int m = 1; m < 32; m <<= 1) s += __shfl_xor(s, m);
            if (tid == 0) lossg[idx] = s;
        }
    }
}

// ---------------------------------------------------------------------------
// loss stage 1: 64 blocks x 256 thr, one float4/thread, fixed-order tree
// ---------------------------------------------------------------------------
__global__ __launch_bounds__(256) void loss_part(
    const float* __restrict__ lossg, float* __restrict__ part) {
    __shared__ float sr[256];
    const int tid = threadIdx.x;
    float4 v = ((const float4*)lossg)[blockIdx.x * 256 + tid];
    sr[tid] = ((v.x + v.y) + (v.z + v.w));
    __syncthreads();
    for (int st = 128; st > 0; st >>= 1) {
        if (tid < st) sr[tid] += sr[tid + st];
        __syncthreads();
    }
    if (tid == 0) part[blockIdx.x] = sr[0];
}

// ---------------------------------------------------------------------------
// loss stage 2: deterministic final (64 partials + pad count)
// ---------------------------------------------------------------------------
__global__ __launch_bounds__(256) void final_kernel(
    const int* __restrict__ pad, const float* __restrict__ part,
    float* __restrict__ out_l) {
    __shared__ int mr[256];
    const int tid = threadIdx.x;
    int m = 0;
#pragma unroll
    for (int i = 0; i < 32; ++i) m += 1 - pad[tid * 32 + i];
    mr[tid] = m;
    __syncthreads();
    for (int st = 128; st > 0; st >>= 1) {
        if (tid < st) mr[tid] += mr[tid + st];
        __syncthreads();
    }
    if (tid == 0) {
        float s = 0.f;
#pragma unroll
        for (int i = 0; i < 64; ++i) s += part[i];
        float k = s / (float)mr[0];
        out_l[0] = k;
        out_l[1] = k;
        out_l[2] = k + k;
    }
}

// ---------------------------------------------------------------------------
extern "C" void kernel_launch(void* const* d_in, const int* in_sizes, int n_in,
                              void* d_out, int out_size, void* d_ws, size_t ws_size,
                              hipStream_t stream) {
    const float* x = (const float*)d_in[0];
    const int* pad = (const int*)d_in[1];
    const float* cb = (const float*)d_in[2];
    float* out = (float*)d_out;
    float* ws = (float*)d_ws;

    float* ws_c2a = ws + OFF_C2A;
    float* ws_c2b = ws + OFF_C2B;
    float* ws_lossg = ws + OFF_LOSSG;
    int* ws_cnt = (int*)(ws + OFF_CNT);
    int* ws_flags = (int*)(ws + OFF_FLAGS);
    f16* cbh = (f16*)(ws + OFF_CBH);
    float* ws_part = ws + OFF_PART;

    prep_kernel<<<NV * NG / 16, 256, 0, stream>>>(cb, cbh, ws_c2a, ws_c2b,
                                                  ws_cnt);
    mfma_gemm<<<(BT / BM) * NG, 256, 0, stream>>>(x, cbh, cb, ws_c2b, pad,
                                                  out + OUT_IDS, out + OUT_Q,
                                                  ws_lossg, ws_cnt, ws_flags);
    recheck<<<2048, 256, 0, stream>>>(x, pad, cb, ws_c2a, ws_cnt, ws_flags,
                                      out + OUT_IDS, out + OUT_Q, ws_lossg);
    loss_part<<<64, 256, 0, stream>>>(ws_lossg, ws_part);
    final_kernel<<<1, 256, 0, stream>>>(pad, ws_part, out + OUT_L);
}